// Round 19
// baseline (124.268 us; speedup 1.0000x reference)
//
#include <hip/hip_runtime.h>
#include <hip/hip_bf16.h>
#include <math.h>

#define NQ 13294
#define NV 13294
#define M_ROWS (2*NQ)     // 26588
#define MP 26624

typedef __attribute__((ext_vector_type(8))) short bf16x8;
typedef __attribute__((ext_vector_type(4))) float f32x4;
typedef __attribute__((ext_vector_type(2))) float f32x2;

__device__ __forceinline__ float bfu_lo(unsigned int u){ return __uint_as_float(u << 16); }
__device__ __forceinline__ float bfu_hi(unsigned int u){ return __uint_as_float(u & 0xffff0000u); }
__device__ __forceinline__ unsigned short f2bf(float f){
  unsigned int u = __float_as_uint(f);
  u += 0x7fffu + ((u >> 16) & 1u);   // RNE
  return (unsigned short)(u >> 16);
}
__device__ __forceinline__ unsigned int pk2(float a, float b){
  return (unsigned int)f2bf(a) | ((unsigned int)f2bf(b) << 16);
}
__device__ __forceinline__ void gl_lds16(const void* g, unsigned short* l) {
  __builtin_amdgcn_global_load_lds(
      (const __attribute__((address_space(1))) unsigned int*)g,
      (__attribute__((address_space(3))) unsigned int*)l, 16, 0, 0);
}

// ---- prep: weights only (transposes + wu copy + bias_c) ----
__global__ __launch_bounds__(256) void prep_w(
    const float* __restrict__ wv, const float* __restrict__ wo,
    const float* __restrict__ wa, const float* __restrict__ wu,
    const float* __restrict__ wf, unsigned short* __restrict__ wt,
    float* __restrict__ bias_c,
    const float* __restrict__ b_out, const float* __restrict__ b_ffn)
{
  const int bx = blockIdx.x;
  if (bx < 64) {
    for (int t = bx * 256 + threadIdx.x; t < 294912; t += 64 * 256) {
      if (t < 229376) {
        const float* src; int Nn; int base;
        if      (t < 65536)  { src = wv; Nn = 256; base = 0; }
        else if (t < 131072) { src = wo; Nn = 256; base = 65536; }
        else if (t < 163840) { src = wa; Nn = 128; base = 131072; }
        else                 { src = wf; Nn = 256; base = 163840; }
        const int local = t - base;
        const int n = local >> 8, k = local & 255;
        wt[t] = f2bf(src[k * Nn + n]);
      } else {
        wt[t] = f2bf(wu[t - 229376]);
      }
    }
  } else {
    const int n = threadIdx.x;
    float acc = b_ffn[n];
    #pragma unroll 8
    for (int k = 0; k < 256; ++k)
      acc = fmaf(b_out[k], wf[k * 256 + n], acc);
    bias_c[n] = acc;
  }
}

// LDS map (64 KB): bytes [0,32768) = A region (f32: 2 tiles x 16KB | bf16: 4 tiles x 8KB)
//                  bytes [32768,65536) = B bf16 4 tiles x 8KB
// ---- merged GEMM: v (f32 A -> fp8 out) | oa (f32 q,p double-pass -> bf16) | Wof ----
__global__ __launch_bounds__(256) void gemm_voa3(
    const float* __restrict__ value, const float* __restrict__ query,
    const float* __restrict__ qpos,
    const unsigned short* __restrict__ wv_t, const unsigned short* __restrict__ woa_t,
    const unsigned short* __restrict__ wf_t, const unsigned short* __restrict__ wu_bf,
    const float* __restrict__ b_value, const float* __restrict__ b_off,
    const float* __restrict__ b_attn,
    unsigned char* __restrict__ vbuf8, unsigned short* __restrict__ oa,
    unsigned short* __restrict__ wof_t)
{
  __shared__ unsigned short lds[32768];

  const int bx = blockIdx.x;
  const int mode = (bx < 1664) ? 0 : (bx < 4160) ? 1 : 2;
  const int lin  = (mode == 0) ? bx : (mode == 1) ? bx - 1664 : bx - 4160;
  const int nwg  = (mode == 0) ? 1664 : (mode == 1) ? 2496 : 16;
  const int ncol = (mode == 0) ? 4 : (mode == 1) ? 6 : 4;
  const unsigned short* Bt = (mode == 0) ? wv_t : (mode == 1) ? woa_t : wu_bf;

  const int swz  = (lin & 7) * (nwg >> 3) + (lin >> 3);
  const int brow = (swz / ncol) * 64;
  const int bcol = (swz % ncol) * 64;

  const int tid  = threadIdx.x;
  const int wid  = tid >> 6, lane = tid & 63;
  const int wr   = wid >> 1, wc = wid & 1;
  const int fr   = lane & 15, fg = lane >> 4;

  // stage B (all 4 tiles, bf16)
  {
    const int r0 = lane >> 3, slot = lane & 7;
    #pragma unroll
    for (int t = 0; t < 4; ++t)
      #pragma unroll
      for (int c = 0; c < 2; ++c) {
        const int row = (wid * 2 + c) * 8 + r0;
        const int gsl = slot ^ (row & 7);
        gl_lds16(Bt + (size_t)(bcol + row) * 256 + t * 64 + (gsl << 3),
                 &lds[16384 + t * 4096 + (wid * 2 + c) * 512]);
      }
  }

  f32x4 acc[2][2];
  #pragma unroll
  for (int m = 0; m < 2; ++m)
    #pragma unroll
    for (int n = 0; n < 2; ++n)
      acc[m][n] = (f32x4){0.f, 0.f, 0.f, 0.f};

  if (mode == 2) {
    // bf16 A path (wf_t)
    {
      const int r0 = lane >> 3, slot = lane & 7;
      #pragma unroll
      for (int t = 0; t < 4; ++t)
        #pragma unroll
        for (int c = 0; c < 2; ++c) {
          const int row = (wid * 2 + c) * 8 + r0;
          const int gsl = slot ^ (row & 7);
          gl_lds16(wf_t + (size_t)(brow + row) * 256 + t * 64 + (gsl << 3),
                   &lds[t * 4096 + (wid * 2 + c) * 512]);
        }
    }
    __syncthreads();
    #pragma unroll
    for (int t = 0; t < 4; ++t) {
      const char* as = (const char*)&lds[t * 4096];
      const char* bs = (const char*)&lds[16384 + t * 4096];
      #pragma unroll
      for (int kk = 0; kk < 2; ++kk) {
        const int kb = kk * 64 + fg * 16;
        bf16x8 af[2], bfv[2];
        #pragma unroll
        for (int m = 0; m < 2; ++m) {
          const int r = wr * 32 + m * 16 + fr;
          af[m] = *(const bf16x8*)(as + r * 128 + (kb ^ ((r & 7) << 4)));
        }
        #pragma unroll
        for (int n = 0; n < 2; ++n) {
          const int r = wc * 32 + n * 16 + fr;
          bfv[n] = *(const bf16x8*)(bs + r * 128 + (kb ^ ((r & 7) << 4)));
        }
        #pragma unroll
        for (int m = 0; m < 2; ++m)
          #pragma unroll
          for (int n = 0; n < 2; ++n)
            acc[m][n] = __builtin_amdgcn_mfma_f32_16x16x32_bf16(af[m], bfv[n], acc[m][n], 0, 0, 0);
      }
    }
  } else {
    // f32 A path: passes over {value} or {query, qpos}, K in halves of 128
    const int npass = (mode == 0) ? 1 : 2;
    for (int ps = 0; ps < npass; ++ps) {
      const float* S = (mode == 0) ? value : (ps == 0 ? query : qpos);
      for (int half = 0; half < 2; ++half) {
        if (ps | half) __syncthreads();     // A-region readers done
        // stage A f32: 2 tiles x 16KB; 1KB (4 rows) per gl_lds
        {
          const int rl = lane >> 4;         // 0..3
          const int sl = lane & 15;         // 16B slot
          #pragma unroll
          for (int t2 = 0; t2 < 2; ++t2) {
            const int kt = half * 2 + t2;
            #pragma unroll
            for (int i = 0; i < 4; ++i) {
              const int c = wid * 4 + i;            // chunk 0..15
              const int row = c * 4 + rl;           // 0..63
              const int gr = min(brow + row, M_ROWS - 1);
              const int gsl = sl ^ (row & 7);
              gl_lds16(S + (size_t)gr * 256 + kt * 64 + gsl * 4,
                       &lds[t2 * 8192 + c * 512]);
            }
          }
        }
        __syncthreads();
        // compute 2 tiles, converting f32->bf16 in fragment load
        #pragma unroll
        for (int t2 = 0; t2 < 2; ++t2) {
          const int kt = half * 2 + t2;
          const char* as = (const char*)&lds[t2 * 8192];
          const char* bs = (const char*)&lds[16384 + kt * 4096];
          #pragma unroll
          for (int kk = 0; kk < 2; ++kk) {
            const int s  = kk * 8 + fg * 2;
            const int kb = kk * 64 + fg * 16;
            bf16x8 af[2], bfv[2];
            #pragma unroll
            for (int m = 0; m < 2; ++m) {
              const int r  = wr * 32 + m * 16 + fr;
              const int e7 = r & 7;
              f32x4 a0 = *(const f32x4*)(as + r * 256 + ((s       ^ e7) << 4));
              f32x4 a1 = *(const f32x4*)(as + r * 256 + (((s + 1) ^ e7) << 4));
              union { unsigned int u[4]; bf16x8 h; } cv;
              cv.u[0] = pk2(a0[0], a0[1]); cv.u[1] = pk2(a0[2], a0[3]);
              cv.u[2] = pk2(a1[0], a1[1]); cv.u[3] = pk2(a1[2], a1[3]);
              af[m] = cv.h;
            }
            #pragma unroll
            for (int n = 0; n < 2; ++n) {
              const int r = wc * 32 + n * 16 + fr;
              bfv[n] = *(const bf16x8*)(bs + r * 128 + (kb ^ ((r & 7) << 4)));
            }
            #pragma unroll
            for (int m = 0; m < 2; ++m)
              #pragma unroll
              for (int n = 0; n < 2; ++n)
                acc[m][n] = __builtin_amdgcn_mfma_f32_16x16x32_bf16(af[m], bfv[n], acc[m][n], 0, 0, 0);
          }
        }
      }
    }
  }

  // epilogue
  __syncthreads();
  float* csh = (float*)lds;
  const int c0 = bcol + wc * 32 + fr;
  const int c1 = c0 + 16;
  float bn0 = 0.f, bn1 = 0.f;
  if (mode == 0) { bn0 = b_value[c0]; bn1 = b_value[c1]; }
  else if (mode == 1) {
    bn0 = (c0 < 256) ? b_off[c0] : b_attn[c0 - 256];
    bn1 = (c1 < 256) ? b_off[c1] : b_attn[c1 - 256];
  }
  #pragma unroll
  for (int m = 0; m < 2; ++m)
    #pragma unroll
    for (int j = 0; j < 4; ++j) {
      const int row = wr * 32 + m * 16 + fg * 4 + j;
      csh[row * 64 + wc * 32 + fr]      = acc[m][0][j] + bn0;
      csh[row * 64 + wc * 32 + 16 + fr] = acc[m][1][j] + bn1;
    }
  __syncthreads();
  #pragma unroll
  for (int i = 0; i < 4; ++i) {
    const int rl = i * 16 + (tid >> 4);
    const int gr = brow + rl;
    if (gr >= M_ROWS && mode != 2) continue;
    const int c4 = (tid & 15) * 4;
    float4 v = *(const float4*)&csh[rl * 64 + c4];
    if (mode == 0) {
      const int head = (bcol + c4) >> 5;
      const int ch   = c4 & 31;
      int r = 0;
      r = __builtin_amdgcn_cvt_pk_fp8_f32(v.x, v.y, r, 0);
      r = __builtin_amdgcn_cvt_pk_fp8_f32(v.z, v.w, r, 1);
      *(int*)&vbuf8[((size_t)head * M_ROWS + gr) * 32 + ch] = r;
    } else if (mode == 1) {
      ushort4 pk = make_ushort4(f2bf(v.x), f2bf(v.y), f2bf(v.z), f2bf(v.w));
      *(ushort4*)&oa[(size_t)gr * 384 + bcol + c4] = pk;
    } else {
      ushort4 pk = make_ushort4(f2bf(v.x), f2bf(v.y), f2bf(v.z), f2bf(v.w));
      *(ushort4*)&wof_t[(size_t)gr * 256 + bcol + c4] = pk;
    }
  }
}

// ---- final GEMM: out = attout@Wof^T + query(f32)@Wffn^T + bias_c ----
__global__ __launch_bounds__(256) void gemm_final2(
    const unsigned short* __restrict__ attout, const unsigned short* __restrict__ wof_t,
    const float* __restrict__ query, const unsigned short* __restrict__ wf_t,
    const float* __restrict__ bias_c, float* __restrict__ C)
{
  __shared__ unsigned short lds[32768];

  const int nwg = 1664;
  const int lin = blockIdx.x;
  const int swz = (lin & 7) * (nwg >> 3) + (lin >> 3);
  const int brow = (swz >> 2) * 64;
  const int bcol = (swz & 3) * 64;

  const int tid  = threadIdx.x;
  const int wid  = tid >> 6, lane = tid & 63;
  const int wr   = wid >> 1, wc = wid & 1;
  const int fr   = lane & 15, fg = lane >> 4;

  auto stage_b = [&](const unsigned short* Bt) {
    const int r0 = lane >> 3, slot = lane & 7;
    #pragma unroll
    for (int t = 0; t < 4; ++t)
      #pragma unroll
      for (int c = 0; c < 2; ++c) {
        const int row = (wid * 2 + c) * 8 + r0;
        const int gsl = slot ^ (row & 7);
        gl_lds16(Bt + (size_t)(bcol + row) * 256 + t * 64 + (gsl << 3),
                 &lds[16384 + t * 4096 + (wid * 2 + c) * 512]);
      }
  };

  f32x4 acc[2][2];
  #pragma unroll
  for (int m = 0; m < 2; ++m)
    #pragma unroll
    for (int n = 0; n < 2; ++n)
      acc[m][n] = (f32x4){0.f, 0.f, 0.f, 0.f};

  // ---- pass 1: attout (bf16) @ wof_t ----
  stage_b(wof_t);
  {
    const int r0 = lane >> 3, slot = lane & 7;
    #pragma unroll
    for (int t = 0; t < 4; ++t)
      #pragma unroll
      for (int c = 0; c < 2; ++c) {
        const int row = (wid * 2 + c) * 8 + r0;
        const int gsl = slot ^ (row & 7);
        gl_lds16(attout + (size_t)(brow + row) * 256 + t * 64 + (gsl << 3),
                 &lds[t * 4096 + (wid * 2 + c) * 512]);
      }
  }
  __syncthreads();
  #pragma unroll
  for (int t = 0; t < 4; ++t) {
    const char* as = (const char*)&lds[t * 4096];
    const char* bs = (const char*)&lds[16384 + t * 4096];
    #pragma unroll
    for (int kk = 0; kk < 2; ++kk) {
      const int kb = kk * 64 + fg * 16;
      bf16x8 af[2], bfv[2];
      #pragma unroll
      for (int m = 0; m < 2; ++m) {
        const int r = wr * 32 + m * 16 + fr;
        af[m] = *(const bf16x8*)(as + r * 128 + (kb ^ ((r & 7) << 4)));
      }
      #pragma unroll
      for (int n = 0; n < 2; ++n) {
        const int r = wc * 32 + n * 16 + fr;
        bfv[n] = *(const bf16x8*)(bs + r * 128 + (kb ^ ((r & 7) << 4)));
      }
      #pragma unroll
      for (int m = 0; m < 2; ++m)
        #pragma unroll
        for (int n = 0; n < 2; ++n)
          acc[m][n] = __builtin_amdgcn_mfma_f32_16x16x32_bf16(af[m], bfv[n], acc[m][n], 0, 0, 0);
    }
  }

  // ---- pass 2: query (f32) @ wf_t, K halves ----
  for (int half = 0; half < 2; ++half) {
    __syncthreads();                       // previous readers done
    if (half == 0) stage_b(wf_t);          // overwrite B region once
    {
      const int rl = lane >> 4;
      const int sl = lane & 15;
      #pragma unroll
      for (int t2 = 0; t2 < 2; ++t2) {
        const int kt = half * 2 + t2;
        #pragma unroll
        for (int i = 0; i < 4; ++i) {
          const int c = wid * 4 + i;
          const int row = c * 4 + rl;
          const int gr = min(brow + row, M_ROWS - 1);
          const int gsl = sl ^ (row & 7);
          gl_lds16(query + (size_t)gr * 256 + kt * 64 + gsl * 4,
                   &lds[t2 * 8192 + c * 512]);
        }
      }
    }
    __syncthreads();
    #pragma unroll
    for (int t2 = 0; t2 < 2; ++t2) {
      const int kt = half * 2 + t2;
      const char* as = (const char*)&lds[t2 * 8192];
      const char* bs = (const char*)&lds[16384 + kt * 4096];
      #pragma unroll
      for (int kk = 0; kk < 2; ++kk) {
        const int s  = kk * 8 + fg * 2;
        const int kb = kk * 64 + fg * 16;
        bf16x8 af[2], bfv[2];
        #pragma unroll
        for (int m = 0; m < 2; ++m) {
          const int r  = wr * 32 + m * 16 + fr;
          const int e7 = r & 7;
          f32x4 a0 = *(const f32x4*)(as + r * 256 + ((s       ^ e7) << 4));
          f32x4 a1 = *(const f32x4*)(as + r * 256 + (((s + 1) ^ e7) << 4));
          union { unsigned int u[4]; bf16x8 h; } cv;
          cv.u[0] = pk2(a0[0], a0[1]); cv.u[1] = pk2(a0[2], a0[3]);
          cv.u[2] = pk2(a1[0], a1[1]); cv.u[3] = pk2(a1[2], a1[3]);
          af[m] = cv.h;
        }
        #pragma unroll
        for (int n = 0; n < 2; ++n) {
          const int r = wc * 32 + n * 16 + fr;
          bfv[n] = *(const bf16x8*)(bs + r * 128 + (kb ^ ((r & 7) << 4)));
        }
        #pragma unroll
        for (int m = 0; m < 2; ++m)
          #pragma unroll
          for (int n = 0; n < 2; ++n)
            acc[m][n] = __builtin_amdgcn_mfma_f32_16x16x32_bf16(af[m], bfv[n], acc[m][n], 0, 0, 0);
      }
    }
  }

  // epilogue (f32 out)
  __syncthreads();
  float* csh = (float*)lds;
  const int c0 = bcol + wc * 32 + fr;
  const int c1 = c0 + 16;
  const float bn0 = bias_c[c0];
  const float bn1 = bias_c[c1];
  #pragma unroll
  for (int m = 0; m < 2; ++m)
    #pragma unroll
    for (int j = 0; j < 4; ++j) {
      const int row = wr * 32 + m * 16 + fg * 4 + j;
      csh[row * 64 + wc * 32 + fr]      = acc[m][0][j] + bn0;
      csh[row * 64 + wc * 32 + 16 + fr] = acc[m][1][j] + bn1;
    }
  __syncthreads();
  #pragma unroll
  for (int i = 0; i < 4; ++i) {
    const int rl = i * 16 + (tid >> 4);
    const int gr = brow + rl;
    if (gr >= M_ROWS) continue;
    const int c4 = (tid & 15) * 4;
    *(float4*)&C[(size_t)gr * 256 + bcol + c4] = *(const float4*)&csh[rl * 64 + c4];
  }
}

// ---- deformable sampling: fp8 v, 4 lanes/(q,h), paired x-corners ----
__global__ __launch_bounds__(256) void msda7(
    const unsigned char* __restrict__ v, const unsigned short* __restrict__ oa,
    const float* __restrict__ ref, unsigned short* __restrict__ attout)
{
  constexpr int LW[4] = {100, 50, 25, 13};
  constexpr int LS[4] = {0, 10000, 12500, 13125};

  __shared__ int2   sidx[64][17];
  __shared__ float4 swt [64][17];

  const int bid   = blockIdx.x;
  const int h     = bid & 7;
  const int chunk = bid >> 3;
  const int tid   = threadIdx.x;
  const int q     = tid >> 2;
  const int c     = tid & 3;
  const int bq    = chunk * 64 + q;
  const bool active = bq < M_ROWS;
  const int b     = (bq >= NQ) ? 1 : 0;

  if (active) {
    const int l = c;
    const int W = LW[l];
    const float fD = (float)W;
    const unsigned short* oarow = oa + (size_t)bq * 384;

    uint2 lg = *(const uint2*)(oarow + 256 + h * 16 + l * 4);
    float g0 = bfu_lo(lg.x), g1 = bfu_hi(lg.x), g2 = bfu_lo(lg.y), g3 = bfu_hi(lg.y);
    float mx = fmaxf(fmaxf(g0, g1), fmaxf(g2, g3));
    mx = fmaxf(mx, __shfl_xor(mx, 1));
    mx = fmaxf(mx, __shfl_xor(mx, 2));
    float e0 = __expf(g0-mx), e1 = __expf(g1-mx), e2 = __expf(g2-mx), e3 = __expf(g3-mx);
    float s = e0 + e1 + e2 + e3;
    s += __shfl_xor(s, 1);
    s += __shfl_xor(s, 2);
    const float inv = 1.f / s;
    const float ee[4] = {e0*inv, e1*inv, e2*inv, e3*inv};

    uint4 ov = *(const uint4*)(oarow + h * 32 + l * 8);
    const float oxy[8] = {bfu_lo(ov.x), bfu_hi(ov.x), bfu_lo(ov.y), bfu_hi(ov.y),
                          bfu_lo(ov.z), bfu_hi(ov.z), bfu_lo(ov.w), bfu_hi(ov.w)};
    const float rx = ref[(size_t)bq * 8 + l * 2];
    const float ry = ref[(size_t)bq * 8 + l * 2 + 1];
    const int rowbase = b * NV + LS[l];

    #pragma unroll
    for (int j = 0; j < 4; ++j) {
      const float x = fmaf(rx, fD, oxy[2*j])   - 0.5f;
      const float y = fmaf(ry, fD, oxy[2*j+1]) - 0.5f;
      const float x0f = floorf(x), y0f = floorf(y);
      const float lx = x - x0f, ly = y - y0f;
      const int x0 = (int)x0f, y0 = (int)y0f;
      const int y1 = y0 + 1;
      const int xbase = min(max(x0, 0), W - 2);
      const float wx0 = 1.f - lx, wx1 = lx;
      const float we0 = (x0 == xbase     ? wx0 : 0.f) + (x0 == xbase - 1 ? wx1 : 0.f);
      const float we1 = (x0 == xbase + 1 ? wx0 : 0.f) + (x0 == xbase     ? wx1 : 0.f);
      const int cy0 = min(max(y0, 0), W - 1), cy1 = min(max(y1, 0), W - 1);
      const float wy0 = (y0 >= 0 && y0 < W) ? (1.f - ly) : 0.f;
      const float wy1 = (y1 >= 0 && y1 < W) ? ly : 0.f;
      const float wt = ee[j];
      const int p = l * 4 + j;
      sidx[q][p] = make_int2((rowbase + cy0 * W + xbase) * 32,
                             (rowbase + cy1 * W + xbase) * 32);
      swt[q][p] = make_float4(wt * wy0 * we0, wt * wy0 * we1,
                              wt * wy1 * we0, wt * wy1 * we1);
    }
  }
  __syncthreads();

  if (active) {
    const unsigned char* vb = v + (size_t)h * M_ROWS * 32 + c * 16;
    const int el = c >> 1;
    f32x2 acc2[8];
    #pragma unroll
    for (int k = 0; k < 8; ++k) acc2[k] = (f32x2){0.f, 0.f};
    #pragma unroll
    for (int p = 0; p < 16; ++p) {
      const int2   ix = sidx[q][p];
      const float4 w4 = swt[q][p];
      uint4 r0 = *(const uint4*)(vb + ix.x);
      uint4 r1 = *(const uint4*)(vb + ix.y);
      const float wa = el ? w4.y : w4.x;
      const float wb = el ? w4.w : w4.z;
      const f32x2 wav = (f32x2){wa, wa};
      const f32x2 wbv = (f32x2){wb, wb};
      acc2[0] = wav * __builtin_amdgcn_cvt_pk_f32_fp8(r0.x, 0) + acc2[0];
      acc2[1] = wav * __builtin_amdgcn_cvt_pk_f32_fp8(r0.x, 1) + acc2[1];
      acc2[2] = wav * __builtin_amdgcn_cvt_pk_f32_fp8(r0.y, 0) + acc2[2];
      acc2[3] = wav * __builtin_amdgcn_cvt_pk_f32_fp8(r0.y, 1) + acc2[3];
      acc2[4] = wav * __builtin_amdgcn_cvt_pk_f32_fp8(r0.z, 0) + acc2[4];
      acc2[5] = wav * __builtin_amdgcn_cvt_pk_f32_fp8(r0.z, 1) + acc2[5];
      acc2[6] = wav * __builtin_amdgcn_cvt_pk_f32_fp8(r0.w, 0) + acc2[6];
      acc2[7] = wav * __builtin_amdgcn_cvt_pk_f32_fp8(r0.w, 1) + acc2[7];
      acc2[0] = wbv * __builtin_amdgcn_cvt_pk_f32_fp8(r1.x, 0) + acc2[0];
      acc2[1] = wbv * __builtin_amdgcn_cvt_pk_f32_fp8(r1.x, 1) + acc2[1];
      acc2[2] = wbv * __builtin_amdgcn_cvt_pk_f32_fp8(r1.y, 0) + acc2[2];
      acc2[3] = wbv * __builtin_amdgcn_cvt_pk_f32_fp8(r1.y, 1) + acc2[3];
      acc2[4] = wbv * __builtin_amdgcn_cvt_pk_f32_fp8(r1.z, 0) + acc2[4];
      acc2[5] = wbv * __builtin_amdgcn_cvt_pk_f32_fp8(r1.z, 1) + acc2[5];
      acc2[6] = wbv * __builtin_amdgcn_cvt_pk_f32_fp8(r1.w, 0) + acc2[6];
      acc2[7] = wbv * __builtin_amdgcn_cvt_pk_f32_fp8(r1.w, 1) + acc2[7];
    }
    #pragma unroll
    for (int k = 0; k < 8; ++k) {
      acc2[k][0] += __shfl_xor(acc2[k][0], 2);
      acc2[k][1] += __shfl_xor(acc2[k][1], 2);
    }
    if (c < 2) {
      uint4 pkA, pkB;
      pkA.x = pk2(acc2[0][0], acc2[0][1]);
      pkA.y = pk2(acc2[1][0], acc2[1][1]);
      pkA.z = pk2(acc2[2][0], acc2[2][1]);
      pkA.w = pk2(acc2[3][0], acc2[3][1]);
      pkB.x = pk2(acc2[4][0], acc2[4][1]);
      pkB.y = pk2(acc2[5][0], acc2[5][1]);
      pkB.z = pk2(acc2[6][0], acc2[6][1]);
      pkB.w = pk2(acc2[7][0], acc2[7][1]);
      unsigned short* dst = attout + (size_t)bq * 256 + h * 32 + c * 16;
      *(uint4*)dst = pkA;
      *(uint4*)(dst + 8) = pkB;
    }
  }
}

extern "C" void kernel_launch(void* const* d_in, const int* in_sizes, int n_in,
                              void* d_out, int out_size, void* d_ws, size_t ws_size,
                              hipStream_t stream) {
  const float* query  = (const float*)d_in[0];
  const float* value  = (const float*)d_in[2];
  const float* qpos   = (const float*)d_in[3];
  const float* refpts = (const float*)d_in[4];
  const float* W_value = (const float*)d_in[8];
  const float* b_value = (const float*)d_in[9];
  const float* W_off   = (const float*)d_in[10];
  const float* b_off   = (const float*)d_in[11];
  const float* W_attn  = (const float*)d_in[12];
  const float* b_attn  = (const float*)d_in[13];
  const float* W_out   = (const float*)d_in[14];
  const float* b_out   = (const float*)d_in[15];
  const float* W_ffn   = (const float*)d_in[16];
  const float* b_ffn   = (const float*)d_in[17];
  float* out = (float*)d_out;

  // workspace layout (~42 MB)
  unsigned short* oa    = (unsigned short*)d_ws;                     // (MP,384) bf16
  unsigned char*  vbuf8 = (unsigned char*)(oa + (size_t)MP * 384);   // [8][M][32] fp8
  unsigned short* AB1   = (unsigned short*)(vbuf8 + (size_t)8 * M_ROWS * 32); // attout bf16 (MP rows)
  unsigned short* wts   = AB1 + (size_t)MP * 256;                    // 294912 shorts
  unsigned short* wv_t  = wts;
  unsigned short* woa_t = wts + 65536;
  unsigned short* wf_t  = wts + 163840;
  unsigned short* wu_bf = wts + 229376;
  unsigned short* wof_t = wts + 294912;
  float*          bias_c = (float*)(wof_t + 65536);

  const dim3 blk(256);

  // weights-only prep
  prep_w<<<dim3(65), blk, 0, stream>>>(W_value, W_off, W_attn, W_out, W_ffn,
                                       wts, bias_c, b_out, b_ffn);

  // merged: v-GEMM (f32 value -> fp8) + oa-GEMM (f32 q,p double-pass) + Wof
  gemm_voa3<<<dim3(1664 + 2496 + 16), blk, 0, stream>>>(
      value, query, qpos, wv_t, woa_t, wf_t, wu_bf,
      b_value, b_off, b_attn, vbuf8, oa, wof_t);

  // deformable sampling -> attout bf16
  msda7<<<dim3(8 * 416), blk, 0, stream>>>(vbuf8, oa, refpts, AB1);

  // out = attout@Wof^T + query@Wffn^T + bias_c
  gemm_final2<<<dim3(1664), blk, 0, stream>>>(AB1, wof_t, query, wf_t, bias_c, out);
}

// Round 20
// 110.207 us; speedup vs baseline: 1.1276x; 1.1276x over previous
//
#include <hip/hip_runtime.h>
#include <hip/hip_bf16.h>
#include <math.h>

#define NQ 13294
#define NV 13294
#define M_ROWS (2*NQ)     // 26588
#define MP 26624          // padded row count (416*64)

typedef __attribute__((ext_vector_type(8))) short bf16x8;
typedef __attribute__((ext_vector_type(4))) float f32x4;
typedef __attribute__((ext_vector_type(2))) float f32x2;

__device__ __forceinline__ float4 ld4nt(const float* p){
  float4 v;
  v.x = __builtin_nontemporal_load(p);
  v.y = __builtin_nontemporal_load(p + 1);
  v.z = __builtin_nontemporal_load(p + 2);
  v.w = __builtin_nontemporal_load(p + 3);
  return v;
}
__device__ __forceinline__ float bfu_lo(unsigned int u){ return __uint_as_float(u << 16); }
__device__ __forceinline__ float bfu_hi(unsigned int u){ return __uint_as_float(u & 0xffff0000u); }
__device__ __forceinline__ unsigned short f2bf(float f){
  unsigned int u = __float_as_uint(f);
  u += 0x7fffu + ((u >> 16) & 1u);   // RNE
  return (unsigned short)(u >> 16);
}
__device__ __forceinline__ unsigned int pk2(float a, float b){
  return (unsigned int)f2bf(a) | ((unsigned int)f2bf(b) << 16);
}
__device__ __forceinline__ void gl_lds16(const unsigned short* g, unsigned short* l) {
  __builtin_amdgcn_global_load_lds(
      (const __attribute__((address_space(1))) unsigned int*)g,
      (__attribute__((address_space(3))) unsigned int*)l, 16, 0, 0);
}

// ---- prep, stream-specialized per block range (round-16 structure, nt loads) ----
// [0,1280): value -> val_bf (bf16, 16B stores)
// [1280,3072): query,qpos -> q_bf (q+p) and q2_bf (q)
// [3072,3136): weight transposes + wu copy
// 3136: bias_c
__global__ __launch_bounds__(256) void prep_split(
    const float* __restrict__ value, const float* __restrict__ query,
    const float* __restrict__ qpos,
    unsigned short* __restrict__ val_bf, unsigned short* __restrict__ q_bf,
    unsigned short* __restrict__ q2_bf,
    const float* __restrict__ wv, const float* __restrict__ wo,
    const float* __restrict__ wa, const float* __restrict__ wu,
    const float* __restrict__ wf, unsigned short* __restrict__ wt,
    float* __restrict__ bias_c,
    const float* __restrict__ b_out, const float* __restrict__ b_ffn)
{
  const int bx = blockIdx.x;
  const int NOCT = (M_ROWS * 256) / 8;   // 850,816 octets of 8 elems

  if (bx < 1280) {
    for (int i = bx * 256 + threadIdx.x; i < NOCT; i += 1280 * 256) {
      const int e = i * 8;
      float4 f0 = ld4nt(value + e);
      float4 f1 = ld4nt(value + e + 4);
      uint4 pk;
      pk.x = pk2(f0.x, f0.y); pk.y = pk2(f0.z, f0.w);
      pk.z = pk2(f1.x, f1.y); pk.w = pk2(f1.z, f1.w);
      *(uint4*)(val_bf + e) = pk;
    }
  } else if (bx < 3072) {
    for (int i = (bx - 1280) * 256 + threadIdx.x; i < NOCT; i += 1792 * 256) {
      const int e = i * 8;
      float4 q0 = ld4nt(query + e);
      float4 q1 = ld4nt(query + e + 4);
      float4 p0 = ld4nt(qpos + e);
      float4 p1 = ld4nt(qpos + e + 4);
      uint4 pkq;   // query alone
      pkq.x = pk2(q0.x, q0.y); pkq.y = pk2(q0.z, q0.w);
      pkq.z = pk2(q1.x, q1.y); pkq.w = pk2(q1.z, q1.w);
      *(uint4*)(q2_bf + e) = pkq;
      uint4 pks;   // query + qpos
      pks.x = pk2(q0.x + p0.x, q0.y + p0.y);
      pks.y = pk2(q0.z + p0.z, q0.w + p0.w);
      pks.z = pk2(q1.x + p1.x, q1.y + p1.y);
      pks.w = pk2(q1.z + p1.z, q1.w + p1.w);
      *(uint4*)(q_bf + e) = pks;
    }
  } else if (bx < 3136) {
    for (int t = (bx - 3072) * 256 + threadIdx.x; t < 294912; t += 64 * 256) {
      if (t < 229376) {
        const float* src; int Nn; int base;
        if      (t < 65536)  { src = wv; Nn = 256; base = 0; }
        else if (t < 131072) { src = wo; Nn = 256; base = 65536; }
        else if (t < 163840) { src = wa; Nn = 128; base = 131072; }
        else                 { src = wf; Nn = 256; base = 163840; }
        const int local = t - base;
        const int n = local >> 8, k = local & 255;
        wt[t] = f2bf(src[k * Nn + n]);
      } else {
        wt[t] = f2bf(wu[t - 229376]);   // wu straight copy (coalesced)
      }
    }
  } else {
    // bias_c[n] = sum_k b_out[k]*W_ffn[k][n] + b_ffn[n]
    const int n = threadIdx.x;
    float acc = b_ffn[n];
    #pragma unroll 8
    for (int k = 0; k < 256; ++k)
      acc = fmaf(b_out[k], wf[k * 256 + n], acc);
    bias_c[n] = acc;
  }
}

// ---- merged GEMM dispatch: v (fp8 head-split) | oa (bf16) | Wof (bf16 256x256) ----
__global__ __launch_bounds__(256) void gemm_voa2(
    const unsigned short* __restrict__ val_bf, const unsigned short* __restrict__ q_bf,
    const unsigned short* __restrict__ wv_t, const unsigned short* __restrict__ woa_t,
    const unsigned short* __restrict__ wf_t, const unsigned short* __restrict__ wu_bf,
    const float* __restrict__ b_value, const float* __restrict__ b_off,
    const float* __restrict__ b_attn,
    unsigned char* __restrict__ vbuf8, unsigned short* __restrict__ oa,
    unsigned short* __restrict__ wof_t)
{
  __shared__ unsigned short lds[32768];   // As [0,16384) | Bs [16384,32768)

  const int bx = blockIdx.x;
  const int mode = (bx < 1664) ? 0 : (bx < 4160) ? 1 : 2;
  const int lin  = (mode == 0) ? bx : (mode == 1) ? bx - 1664 : bx - 4160;
  const int nwg  = (mode == 0) ? 1664 : (mode == 1) ? 2496 : 16;
  const int ncol = (mode == 0) ? 4 : (mode == 1) ? 6 : 4;
  const unsigned short* A  = (mode == 0) ? val_bf : (mode == 1) ? q_bf : wf_t;
  const unsigned short* Bt = (mode == 0) ? wv_t : (mode == 1) ? woa_t : wu_bf;

  const int swz  = (lin & 7) * (nwg >> 3) + (lin >> 3);
  const int brow = (swz / ncol) * 64;
  const int bcol = (swz % ncol) * 64;

  const int tid  = threadIdx.x;
  const int wid  = tid >> 6, lane = tid & 63;
  const int wr   = wid >> 1, wc = wid & 1;
  const int fr   = lane & 15, fg = lane >> 4;

  {
    const int r0   = lane >> 3;
    const int slot = lane & 7;
    #pragma unroll
    for (int t = 0; t < 4; ++t) {
      #pragma unroll
      for (int c = 0; c < 2; ++c) {
        const int row = (wid * 2 + c) * 8 + r0;
        const int gsl = slot ^ (row & 7);
        gl_lds16(A  + (size_t)(brow + row) * 256 + t * 64 + (gsl << 3),
                 &lds[t * 4096 + (wid * 2 + c) * 512]);
        gl_lds16(Bt + (size_t)(bcol + row) * 256 + t * 64 + (gsl << 3),
                 &lds[16384 + t * 4096 + (wid * 2 + c) * 512]);
      }
    }
  }
  __syncthreads();

  f32x4 acc[2][2];
  #pragma unroll
  for (int m = 0; m < 2; ++m)
    #pragma unroll
    for (int n = 0; n < 2; ++n)
      acc[m][n] = (f32x4){0.f, 0.f, 0.f, 0.f};

  #pragma unroll
  for (int t = 0; t < 4; ++t) {
    const char* as = (const char*)&lds[t * 4096];
    const char* bs = (const char*)&lds[16384 + t * 4096];
    #pragma unroll
    for (int kk = 0; kk < 2; ++kk) {
      const int kb = kk * 64 + fg * 16;
      bf16x8 af[2], bfv[2];
      #pragma unroll
      for (int m = 0; m < 2; ++m) {
        const int r = wr * 32 + m * 16 + fr;
        af[m] = *(const bf16x8*)(as + r * 128 + (kb ^ ((r & 7) << 4)));
      }
      #pragma unroll
      for (int n = 0; n < 2; ++n) {
        const int r = wc * 32 + n * 16 + fr;
        bfv[n] = *(const bf16x8*)(bs + r * 128 + (kb ^ ((r & 7) << 4)));
      }
      #pragma unroll
      for (int m = 0; m < 2; ++m)
        #pragma unroll
        for (int n = 0; n < 2; ++n)
          acc[m][n] = __builtin_amdgcn_mfma_f32_16x16x32_bf16(af[m], bfv[n], acc[m][n], 0, 0, 0);
    }
  }

  __syncthreads();
  float* csh = (float*)lds;
  const int c0 = bcol + wc * 32 + fr;
  const int c1 = c0 + 16;
  float bn0 = 0.f, bn1 = 0.f;
  if (mode == 0) { bn0 = b_value[c0]; bn1 = b_value[c1]; }
  else if (mode == 1) {
    bn0 = (c0 < 256) ? b_off[c0] : b_attn[c0 - 256];
    bn1 = (c1 < 256) ? b_off[c1] : b_attn[c1 - 256];
  }
  #pragma unroll
  for (int m = 0; m < 2; ++m)
    #pragma unroll
    for (int j = 0; j < 4; ++j) {
      const int row = wr * 32 + m * 16 + fg * 4 + j;
      csh[row * 64 + wc * 32 + fr]      = acc[m][0][j] + bn0;
      csh[row * 64 + wc * 32 + 16 + fr] = acc[m][1][j] + bn1;
    }
  __syncthreads();
  #pragma unroll
  for (int i = 0; i < 4; ++i) {
    const int rl = i * 16 + (tid >> 4);
    const int gr = brow + rl;
    if (gr >= M_ROWS && mode != 2) continue;
    const int c4 = (tid & 15) * 4;
    float4 v = *(const float4*)&csh[rl * 64 + c4];
    if (mode == 0) {
      const int head = (bcol + c4) >> 5;
      const int ch   = c4 & 31;
      int r = 0;
      r = __builtin_amdgcn_cvt_pk_fp8_f32(v.x, v.y, r, 0);
      r = __builtin_amdgcn_cvt_pk_fp8_f32(v.z, v.w, r, 1);
      *(int*)&vbuf8[((size_t)head * M_ROWS + gr) * 32 + ch] = r;
    } else if (mode == 1) {
      ushort4 pk = make_ushort4(f2bf(v.x), f2bf(v.y), f2bf(v.z), f2bf(v.w));
      *(ushort4*)&oa[(size_t)gr * 384 + bcol + c4] = pk;
    } else {
      ushort4 pk = make_ushort4(f2bf(v.x), f2bf(v.y), f2bf(v.z), f2bf(v.w));
      *(ushort4*)&wof_t[(size_t)gr * 256 + bcol + c4] = pk;
    }
  }
}

// ---- final fused GEMM: out = attout@Wof^T + query_bf@Wffn^T + bias_c  (K=512) ----
__global__ __launch_bounds__(256) void gemm_final(
    const unsigned short* __restrict__ A1, const unsigned short* __restrict__ B1,
    const unsigned short* __restrict__ A2, const unsigned short* __restrict__ B2,
    const float* __restrict__ bias_c, float* __restrict__ C)
{
  __shared__ unsigned short lds[32768];

  const int nwg = 1664;
  const int lin = blockIdx.x;
  const int swz = (lin & 7) * (nwg >> 3) + (lin >> 3);
  const int brow = (swz >> 2) * 64;
  const int bcol = (swz & 3) * 64;

  const int tid  = threadIdx.x;
  const int wid  = tid >> 6, lane = tid & 63;
  const int wr   = wid >> 1, wc = wid & 1;
  const int fr   = lane & 15, fg = lane >> 4;

  auto stage = [&](const unsigned short* A, const unsigned short* Bt) {
    const int r0   = lane >> 3;
    const int slot = lane & 7;
    #pragma unroll
    for (int t = 0; t < 4; ++t) {
      #pragma unroll
      for (int c = 0; c < 2; ++c) {
        const int row = (wid * 2 + c) * 8 + r0;
        const int gsl = slot ^ (row & 7);
        gl_lds16(A  + (size_t)(brow + row) * 256 + t * 64 + (gsl << 3),
                 &lds[t * 4096 + (wid * 2 + c) * 512]);
        gl_lds16(Bt + (size_t)(bcol + row) * 256 + t * 64 + (gsl << 3),
                 &lds[16384 + t * 4096 + (wid * 2 + c) * 512]);
      }
    }
  };

  f32x4 acc[2][2];
  #pragma unroll
  for (int m = 0; m < 2; ++m)
    #pragma unroll
    for (int n = 0; n < 2; ++n)
      acc[m][n] = (f32x4){0.f, 0.f, 0.f, 0.f};

  auto compute = [&]() {
    #pragma unroll
    for (int t = 0; t < 4; ++t) {
      const char* as = (const char*)&lds[t * 4096];
      const char* bs = (const char*)&lds[16384 + t * 4096];
      #pragma unroll
      for (int kk = 0; kk < 2; ++kk) {
        const int kb = kk * 64 + fg * 16;
        bf16x8 af[2], bfv[2];
        #pragma unroll
        for (int m = 0; m < 2; ++m) {
          const int r = wr * 32 + m * 16 + fr;
          af[m] = *(const bf16x8*)(as + r * 128 + (kb ^ ((r & 7) << 4)));
        }
        #pragma unroll
        for (int n = 0; n < 2; ++n) {
          const int r = wc * 32 + n * 16 + fr;
          bfv[n] = *(const bf16x8*)(bs + r * 128 + (kb ^ ((r & 7) << 4)));
        }
        #pragma unroll
        for (int m = 0; m < 2; ++m)
          #pragma unroll
          for (int n = 0; n < 2; ++n)
            acc[m][n] = __builtin_amdgcn_mfma_f32_16x16x32_bf16(af[m], bfv[n], acc[m][n], 0, 0, 0);
      }
    }
  };

  stage(A1, B1);
  __syncthreads();
  compute();
  __syncthreads();          // all LDS reads done before restage
  stage(A2, B2);
  __syncthreads();
  compute();

  // epilogue
  __syncthreads();
  float* csh = (float*)lds;
  const int c0 = bcol + wc * 32 + fr;
  const int c1 = c0 + 16;
  const float bn0 = bias_c[c0];
  const float bn1 = bias_c[c1];
  #pragma unroll
  for (int m = 0; m < 2; ++m)
    #pragma unroll
    for (int j = 0; j < 4; ++j) {
      const int row = wr * 32 + m * 16 + fg * 4 + j;
      csh[row * 64 + wc * 32 + fr]      = acc[m][0][j] + bn0;
      csh[row * 64 + wc * 32 + 16 + fr] = acc[m][1][j] + bn1;
    }
  __syncthreads();
  #pragma unroll
  for (int i = 0; i < 4; ++i) {
    const int rl = i * 16 + (tid >> 4);
    const int gr = brow + rl;
    if (gr >= M_ROWS) continue;
    const int c4 = (tid & 15) * 4;
    *(float4*)&C[(size_t)gr * 256 + bcol + c4] = *(const float4*)&csh[rl * 64 + c4];
  }
}

// ---- deformable sampling: fp8 v, 4 lanes/(q,h), paired x-corners ----
__global__ __launch_bounds__(256) void msda7(
    const unsigned char* __restrict__ v, const unsigned short* __restrict__ oa,
    const float* __restrict__ ref, unsigned short* __restrict__ attout)
{
  constexpr int LW[4] = {100, 50, 25, 13};
  constexpr int LS[4] = {0, 10000, 12500, 13125};

  __shared__ int2   sidx[64][17];
  __shared__ float4 swt [64][17];

  const int bid   = blockIdx.x;
  const int h     = bid & 7;          // head == XCD under %8 round-robin
  const int chunk = bid >> 3;
  const int tid   = threadIdx.x;
  const int q     = tid >> 2;
  const int c     = tid & 3;
  const int bq    = chunk * 64 + q;
  const bool active = bq < M_ROWS;
  const int b     = (bq >= NQ) ? 1 : 0;

  if (active) {
    const int l = c;
    const int W = LW[l];
    const float fD = (float)W;
    const unsigned short* oarow = oa + (size_t)bq * 384;

    uint2 lg = *(const uint2*)(oarow + 256 + h * 16 + l * 4);
    float g0 = bfu_lo(lg.x), g1 = bfu_hi(lg.x), g2 = bfu_lo(lg.y), g3 = bfu_hi(lg.y);
    float mx = fmaxf(fmaxf(g0, g1), fmaxf(g2, g3));
    mx = fmaxf(mx, __shfl_xor(mx, 1));
    mx = fmaxf(mx, __shfl_xor(mx, 2));
    float e0 = __expf(g0-mx), e1 = __expf(g1-mx), e2 = __expf(g2-mx), e3 = __expf(g3-mx);
    float s = e0 + e1 + e2 + e3;
    s += __shfl_xor(s, 1);
    s += __shfl_xor(s, 2);
    const float inv = 1.f / s;
    const float ee[4] = {e0*inv, e1*inv, e2*inv, e3*inv};

    uint4 ov = *(const uint4*)(oarow + h * 32 + l * 8);
    const float oxy[8] = {bfu_lo(ov.x), bfu_hi(ov.x), bfu_lo(ov.y), bfu_hi(ov.y),
                          bfu_lo(ov.z), bfu_hi(ov.z), bfu_lo(ov.w), bfu_hi(ov.w)};
    const float rx = ref[(size_t)bq * 8 + l * 2];
    const float ry = ref[(size_t)bq * 8 + l * 2 + 1];
    const int rowbase = b * NV + LS[l];

    #pragma unroll
    for (int j = 0; j < 4; ++j) {
      const float x = fmaf(rx, fD, oxy[2*j])   - 0.5f;
      const float y = fmaf(ry, fD, oxy[2*j+1]) - 0.5f;
      const float x0f = floorf(x), y0f = floorf(y);
      const float lx = x - x0f, ly = y - y0f;
      const int x0 = (int)x0f, y0 = (int)y0f;
      const int y1 = y0 + 1;
      const int xbase = min(max(x0, 0), W - 2);
      const float wx0 = 1.f - lx, wx1 = lx;
      const float we0 = (x0 == xbase     ? wx0 : 0.f) + (x0 == xbase - 1 ? wx1 : 0.f);
      const float we1 = (x0 == xbase + 1 ? wx0 : 0.f) + (x0 == xbase     ? wx1 : 0.f);
      const int cy0 = min(max(y0, 0), W - 1), cy1 = min(max(y1, 0), W - 1);
      const float wy0 = (y0 >= 0 && y0 < W) ? (1.f - ly) : 0.f;
      const float wy1 = (y1 >= 0 && y1 < W) ? ly : 0.f;
      const float wt = ee[j];
      const int p = l * 4 + j;
      sidx[q][p] = make_int2((rowbase + cy0 * W + xbase) * 32,
                             (rowbase + cy1 * W + xbase) * 32);
      swt[q][p] = make_float4(wt * wy0 * we0, wt * wy0 * we1,
                              wt * wy1 * we0, wt * wy1 * we1);
    }
  }
  __syncthreads();

  if (active) {
    const unsigned char* vb = v + (size_t)h * M_ROWS * 32 + c * 16;
    const int el = c >> 1;
    f32x2 acc2[8];
    #pragma unroll
    for (int k = 0; k < 8; ++k) acc2[k] = (f32x2){0.f, 0.f};
    #pragma unroll
    for (int p = 0; p < 16; ++p) {
      const int2   ix = sidx[q][p];
      const float4 w4 = swt[q][p];
      uint4 r0 = *(const uint4*)(vb + ix.x);
      uint4 r1 = *(const uint4*)(vb + ix.y);
      const float wa = el ? w4.y : w4.x;
      const float wb = el ? w4.w : w4.z;
      const f32x2 wav = (f32x2){wa, wa};
      const f32x2 wbv = (f32x2){wb, wb};
      acc2[0] = wav * __builtin_amdgcn_cvt_pk_f32_fp8(r0.x, 0) + acc2[0];
      acc2[1] = wav * __builtin_amdgcn_cvt_pk_f32_fp8(r0.x, 1) + acc2[1];
      acc2[2] = wav * __builtin_amdgcn_cvt_pk_f32_fp8(r0.y, 0) + acc2[2];
      acc2[3] = wav * __builtin_amdgcn_cvt_pk_f32_fp8(r0.y, 1) + acc2[3];
      acc2[4] = wav * __builtin_amdgcn_cvt_pk_f32_fp8(r0.z, 0) + acc2[4];
      acc2[5] = wav * __builtin_amdgcn_cvt_pk_f32_fp8(r0.z, 1) + acc2[5];
      acc2[6] = wav * __builtin_amdgcn_cvt_pk_f32_fp8(r0.w, 0) + acc2[6];
      acc2[7] = wav * __builtin_amdgcn_cvt_pk_f32_fp8(r0.w, 1) + acc2[7];
      acc2[0] = wbv * __builtin_amdgcn_cvt_pk_f32_fp8(r1.x, 0) + acc2[0];
      acc2[1] = wbv * __builtin_amdgcn_cvt_pk_f32_fp8(r1.x, 1) + acc2[1];
      acc2[2] = wbv * __builtin_amdgcn_cvt_pk_f32_fp8(r1.y, 0) + acc2[2];
      acc2[3] = wbv * __builtin_amdgcn_cvt_pk_f32_fp8(r1.y, 1) + acc2[3];
      acc2[4] = wbv * __builtin_amdgcn_cvt_pk_f32_fp8(r1.z, 0) + acc2[4];
      acc2[5] = wbv * __builtin_amdgcn_cvt_pk_f32_fp8(r1.z, 1) + acc2[5];
      acc2[6] = wbv * __builtin_amdgcn_cvt_pk_f32_fp8(r1.w, 0) + acc2[6];
      acc2[7] = wbv * __builtin_amdgcn_cvt_pk_f32_fp8(r1.w, 1) + acc2[7];
    }
    #pragma unroll
    for (int k = 0; k < 8; ++k) {
      acc2[k][0] += __shfl_xor(acc2[k][0], 2);
      acc2[k][1] += __shfl_xor(acc2[k][1], 2);
    }
    if (c < 2) {
      uint4 pkA, pkB;
      pkA.x = pk2(acc2[0][0], acc2[0][1]);
      pkA.y = pk2(acc2[1][0], acc2[1][1]);
      pkA.z = pk2(acc2[2][0], acc2[2][1]);
      pkA.w = pk2(acc2[3][0], acc2[3][1]);
      pkB.x = pk2(acc2[4][0], acc2[4][1]);
      pkB.y = pk2(acc2[5][0], acc2[5][1]);
      pkB.z = pk2(acc2[6][0], acc2[6][1]);
      pkB.w = pk2(acc2[7][0], acc2[7][1]);
      unsigned short* dst = attout + (size_t)bq * 256 + h * 32 + c * 16;
      *(uint4*)dst = pkA;
      *(uint4*)(dst + 8) = pkB;
    }
  }
}

extern "C" void kernel_launch(void* const* d_in, const int* in_sizes, int n_in,
                              void* d_out, int out_size, void* d_ws, size_t ws_size,
                              hipStream_t stream) {
  const float* query  = (const float*)d_in[0];
  const float* value  = (const float*)d_in[2];
  const float* qpos   = (const float*)d_in[3];
  const float* refpts = (const float*)d_in[4];
  const float* W_value = (const float*)d_in[8];
  const float* b_value = (const float*)d_in[9];
  const float* W_off   = (const float*)d_in[10];
  const float* b_off   = (const float*)d_in[11];
  const float* W_attn  = (const float*)d_in[12];
  const float* b_attn  = (const float*)d_in[13];
  const float* W_out   = (const float*)d_in[14];
  const float* b_out   = (const float*)d_in[15];
  const float* W_ffn   = (const float*)d_in[16];
  const float* b_ffn   = (const float*)d_in[17];
  float* out = (float*)d_out;

  // workspace layout (~69 MB)
  unsigned short* oa    = (unsigned short*)d_ws;                     // (MP,384) bf16
  unsigned char*  vbuf8 = (unsigned char*)(oa + (size_t)MP * 384);   // [8][M][32] fp8
  unsigned short* AB1   = (unsigned short*)(vbuf8 + (size_t)8 * M_ROWS * 32); // val_bf -> attout
  unsigned short* QB    = AB1 + (size_t)MP * 256;                    // query+qpos bf16
  unsigned short* Q2B   = QB + (size_t)MP * 256;                     // query bf16
  unsigned short* wts   = Q2B + (size_t)MP * 256;                    // 294912 shorts
  unsigned short* wv_t  = wts;
  unsigned short* woa_t = wts + 65536;     // [W_off^T ; W_attn^T]
  unsigned short* wf_t  = wts + 163840;    // W_ffn^T
  unsigned short* wu_bf = wts + 229376;    // W_out bf16 [k][j]
  unsigned short* wof_t = wts + 294912;    // (W_out@W_ffn)^T bf16, 65536 shorts
  float*          bias_c = (float*)(wof_t + 65536);  // 256 f32

  const dim3 blk(256);

  // stream-specialized prep (nt loads)
  prep_split<<<dim3(3137), blk, 0, stream>>>(value, query, qpos, AB1, QB, Q2B,
      W_value, W_off, W_attn, W_out, W_ffn, wts, bias_c, b_out, b_ffn);

  // merged: v-GEMM (fp8) + oa-GEMM (bf16) + Wof GEMM (16 blocks)
  gemm_voa2<<<dim3(1664 + 2496 + 16), blk, 0, stream>>>(
      AB1, QB, wv_t, woa_t, wf_t, wu_bf, b_value, b_off, b_attn, vbuf8, oa, wof_t);

  // deformable sampling -> attout bf16 (overwrites AB1)
  msda7<<<dim3(8 * 416), blk, 0, stream>>>(vbuf8, oa, refpts, AB1);

  // out = attout@Wof^T + query_bf@Wffn^T + bias_c  (K=512, f32 out)
  gemm_final<<<dim3(1664), blk, 0, stream>>>(AB1, wof_t, Q2B, wf_t, bias_c, out);
}

// Round 21
// 107.550 us; speedup vs baseline: 1.1554x; 1.0247x over previous
//
#include <hip/hip_runtime.h>
#include <hip/hip_bf16.h>
#include <math.h>

#define NQ 13294
#define NV 13294
#define M_ROWS (2*NQ)     // 26588
#define MP 26624          // padded row count (416*64)

typedef __attribute__((ext_vector_type(8))) short bf16x8;
typedef __attribute__((ext_vector_type(4))) float f32x4;
typedef __attribute__((ext_vector_type(2))) float f32x2;

__device__ __forceinline__ float bfu_lo(unsigned int u){ return __uint_as_float(u << 16); }
__device__ __forceinline__ float bfu_hi(unsigned int u){ return __uint_as_float(u & 0xffff0000u); }
__device__ __forceinline__ unsigned short f2bf(float f){
  unsigned int u = __float_as_uint(f);
  u += 0x7fffu + ((u >> 16) & 1u);   // RNE
  return (unsigned short)(u >> 16);
}
__device__ __forceinline__ unsigned int pk2(float a, float b){
  return (unsigned int)f2bf(a) | ((unsigned int)f2bf(b) << 16);
}
__device__ __forceinline__ void gl_lds16(const void* g, void* l) {
  __builtin_amdgcn_global_load_lds(
      (const __attribute__((address_space(1))) unsigned int*)g,
      (__attribute__((address_space(3))) unsigned int*)l, 16, 0, 0);
}

// ---- prep via LDS-DMA staging: global_load_lds has no dest VGPR, so the load
// queue is not register-limited (the allocator defeated 6 register-path preps).
// [0,416): value -> val_bf          (64KB f32 DMA -> pack -> 32KB bf16)
// [416,1247): query,qpos -> q_bf(q+p), q2_bf(q)   (32+32KB DMA -> 2x16KB)
// [1247,1311): weight transposes + wu copy
// 1311: bias_c
__global__ __launch_bounds__(256) void prep_dma(
    const float* __restrict__ value, const float* __restrict__ query,
    const float* __restrict__ qpos,
    unsigned short* __restrict__ val_bf, unsigned short* __restrict__ q_bf,
    unsigned short* __restrict__ q2_bf,
    const float* __restrict__ wv, const float* __restrict__ wo,
    const float* __restrict__ wa, const float* __restrict__ wu,
    const float* __restrict__ wf, unsigned short* __restrict__ wt,
    float* __restrict__ bias_c,
    const float* __restrict__ b_out, const float* __restrict__ b_ffn)
{
  __shared__ float lf[16384];   // 64 KB
  const int bx   = blockIdx.x;
  const int tid  = threadIdx.x;
  const int wid  = tid >> 6, lane = tid & 63;
  const size_t TOT = (size_t)M_ROWS * 256;   // 6,806,528 floats per stream

  if (bx < 416) {
    const size_t base = (size_t)bx * 16384;
    #pragma unroll
    for (int i = 0; i < 16; ++i) {
      const int seg = i * 4 + wid;                 // 0..63
      size_t src = base + seg * 256 + lane * 4;
      if (src > TOT - 4) src = TOT - 4;
      gl_lds16(value + src, &lf[seg * 256]);
    }
    __syncthreads();
    #pragma unroll
    for (int r = 0; r < 8; ++r) {
      const int off = r * 2048 + tid * 8;
      const size_t g = base + off;
      if (g + 8 <= TOT) {
        float4 a = *(const float4*)&lf[off];
        float4 b = *(const float4*)&lf[off + 4];
        uint4 pk;
        pk.x = pk2(a.x, a.y); pk.y = pk2(a.z, a.w);
        pk.z = pk2(b.x, b.y); pk.w = pk2(b.z, b.w);
        *(uint4*)(val_bf + g) = pk;
      }
    }
  } else if (bx < 1247) {
    const size_t base = (size_t)(bx - 416) * 8192;
    #pragma unroll
    for (int i = 0; i < 8; ++i) {
      const int seg = i * 4 + wid;                 // 0..31
      size_t src = base + seg * 256 + lane * 4;
      if (src > TOT - 4) src = TOT - 4;
      gl_lds16(query + src, &lf[seg * 256]);
      gl_lds16(qpos  + src, &lf[8192 + seg * 256]);
    }
    __syncthreads();
    #pragma unroll
    for (int r = 0; r < 4; ++r) {
      const int off = r * 2048 + tid * 8;
      const size_t g = base + off;
      if (g + 8 <= TOT) {
        float4 q0 = *(const float4*)&lf[off];
        float4 q1 = *(const float4*)&lf[off + 4];
        float4 p0 = *(const float4*)&lf[8192 + off];
        float4 p1 = *(const float4*)&lf[8192 + off + 4];
        uint4 pkq;
        pkq.x = pk2(q0.x, q0.y); pkq.y = pk2(q0.z, q0.w);
        pkq.z = pk2(q1.x, q1.y); pkq.w = pk2(q1.z, q1.w);
        *(uint4*)(q2_bf + g) = pkq;
        uint4 pks;
        pks.x = pk2(q0.x + p0.x, q0.y + p0.y);
        pks.y = pk2(q0.z + p0.z, q0.w + p0.w);
        pks.z = pk2(q1.x + p1.x, q1.y + p1.y);
        pks.w = pk2(q1.z + p1.z, q1.w + p1.w);
        *(uint4*)(q_bf + g) = pks;
      }
    }
  } else if (bx < 1311) {
    for (int t = (bx - 1247) * 256 + tid; t < 294912; t += 64 * 256) {
      if (t < 229376) {
        const float* src; int Nn; int base2;
        if      (t < 65536)  { src = wv; Nn = 256; base2 = 0; }
        else if (t < 131072) { src = wo; Nn = 256; base2 = 65536; }
        else if (t < 163840) { src = wa; Nn = 128; base2 = 131072; }
        else                 { src = wf; Nn = 256; base2 = 163840; }
        const int local = t - base2;
        const int n = local >> 8, k = local & 255;
        wt[t] = f2bf(src[k * Nn + n]);
      } else {
        wt[t] = f2bf(wu[t - 229376]);   // wu straight copy (coalesced)
      }
    }
  } else {
    // bias_c[n] = sum_k b_out[k]*W_ffn[k][n] + b_ffn[n]
    const int n = tid;
    float acc = b_ffn[n];
    #pragma unroll 8
    for (int k = 0; k < 256; ++k)
      acc = fmaf(b_out[k], wf[k * 256 + n], acc);
    bias_c[n] = acc;
  }
}

// ---- merged GEMM dispatch: v (fp8 head-split) | oa (bf16) | Wof (bf16 256x256) ----
__global__ __launch_bounds__(256) void gemm_voa2(
    const unsigned short* __restrict__ val_bf, const unsigned short* __restrict__ q_bf,
    const unsigned short* __restrict__ wv_t, const unsigned short* __restrict__ woa_t,
    const unsigned short* __restrict__ wf_t, const unsigned short* __restrict__ wu_bf,
    const float* __restrict__ b_value, const float* __restrict__ b_off,
    const float* __restrict__ b_attn,
    unsigned char* __restrict__ vbuf8, unsigned short* __restrict__ oa,
    unsigned short* __restrict__ wof_t)
{
  __shared__ unsigned short lds[32768];   // As [0,16384) | Bs [16384,32768)

  const int bx = blockIdx.x;
  const int mode = (bx < 1664) ? 0 : (bx < 4160) ? 1 : 2;
  const int lin  = (mode == 0) ? bx : (mode == 1) ? bx - 1664 : bx - 4160;
  const int nwg  = (mode == 0) ? 1664 : (mode == 1) ? 2496 : 16;
  const int ncol = (mode == 0) ? 4 : (mode == 1) ? 6 : 4;
  const unsigned short* A  = (mode == 0) ? val_bf : (mode == 1) ? q_bf : wf_t;
  const unsigned short* Bt = (mode == 0) ? wv_t : (mode == 1) ? woa_t : wu_bf;

  const int swz  = (lin & 7) * (nwg >> 3) + (lin >> 3);
  const int brow = (swz / ncol) * 64;
  const int bcol = (swz % ncol) * 64;

  const int tid  = threadIdx.x;
  const int wid  = tid >> 6, lane = tid & 63;
  const int wr   = wid >> 1, wc = wid & 1;
  const int fr   = lane & 15, fg = lane >> 4;

  {
    const int r0   = lane >> 3;
    const int slot = lane & 7;
    #pragma unroll
    for (int t = 0; t < 4; ++t) {
      #pragma unroll
      for (int c = 0; c < 2; ++c) {
        const int row = (wid * 2 + c) * 8 + r0;
        const int gsl = slot ^ (row & 7);
        gl_lds16(A  + (size_t)(brow + row) * 256 + t * 64 + (gsl << 3),
                 &lds[t * 4096 + (wid * 2 + c) * 512]);
        gl_lds16(Bt + (size_t)(bcol + row) * 256 + t * 64 + (gsl << 3),
                 &lds[16384 + t * 4096 + (wid * 2 + c) * 512]);
      }
    }
  }
  __syncthreads();

  f32x4 acc[2][2];
  #pragma unroll
  for (int m = 0; m < 2; ++m)
    #pragma unroll
    for (int n = 0; n < 2; ++n)
      acc[m][n] = (f32x4){0.f, 0.f, 0.f, 0.f};

  #pragma unroll
  for (int t = 0; t < 4; ++t) {
    const char* as = (const char*)&lds[t * 4096];
    const char* bs = (const char*)&lds[16384 + t * 4096];
    #pragma unroll
    for (int kk = 0; kk < 2; ++kk) {
      const int kb = kk * 64 + fg * 16;
      bf16x8 af[2], bfv[2];
      #pragma unroll
      for (int m = 0; m < 2; ++m) {
        const int r = wr * 32 + m * 16 + fr;
        af[m] = *(const bf16x8*)(as + r * 128 + (kb ^ ((r & 7) << 4)));
      }
      #pragma unroll
      for (int n = 0; n < 2; ++n) {
        const int r = wc * 32 + n * 16 + fr;
        bfv[n] = *(const bf16x8*)(bs + r * 128 + (kb ^ ((r & 7) << 4)));
      }
      #pragma unroll
      for (int m = 0; m < 2; ++m)
        #pragma unroll
        for (int n = 0; n < 2; ++n)
          acc[m][n] = __builtin_amdgcn_mfma_f32_16x16x32_bf16(af[m], bfv[n], acc[m][n], 0, 0, 0);
    }
  }

  __syncthreads();
  float* csh = (float*)lds;
  const int c0 = bcol + wc * 32 + fr;
  const int c1 = c0 + 16;
  float bn0 = 0.f, bn1 = 0.f;
  if (mode == 0) { bn0 = b_value[c0]; bn1 = b_value[c1]; }
  else if (mode == 1) {
    bn0 = (c0 < 256) ? b_off[c0] : b_attn[c0 - 256];
    bn1 = (c1 < 256) ? b_off[c1] : b_attn[c1 - 256];
  }
  #pragma unroll
  for (int m = 0; m < 2; ++m)
    #pragma unroll
    for (int j = 0; j < 4; ++j) {
      const int row = wr * 32 + m * 16 + fg * 4 + j;
      csh[row * 64 + wc * 32 + fr]      = acc[m][0][j] + bn0;
      csh[row * 64 + wc * 32 + 16 + fr] = acc[m][1][j] + bn1;
    }
  __syncthreads();
  #pragma unroll
  for (int i = 0; i < 4; ++i) {
    const int rl = i * 16 + (tid >> 4);
    const int gr = brow + rl;
    if (gr >= M_ROWS && mode != 2) continue;
    const int c4 = (tid & 15) * 4;
    float4 v = *(const float4*)&csh[rl * 64 + c4];
    if (mode == 0) {
      const int head = (bcol + c4) >> 5;
      const int ch   = c4 & 31;
      int r = 0;
      r = __builtin_amdgcn_cvt_pk_fp8_f32(v.x, v.y, r, 0);
      r = __builtin_amdgcn_cvt_pk_fp8_f32(v.z, v.w, r, 1);
      *(int*)&vbuf8[((size_t)head * M_ROWS + gr) * 32 + ch] = r;
    } else if (mode == 1) {
      ushort4 pk = make_ushort4(f2bf(v.x), f2bf(v.y), f2bf(v.z), f2bf(v.w));
      *(ushort4*)&oa[(size_t)gr * 384 + bcol + c4] = pk;
    } else {
      ushort4 pk = make_ushort4(f2bf(v.x), f2bf(v.y), f2bf(v.z), f2bf(v.w));
      *(ushort4*)&wof_t[(size_t)gr * 256 + bcol + c4] = pk;
    }
  }
}

// ---- final fused GEMM: out = attout@Wof^T + query_bf@Wffn^T + bias_c  (K=512) ----
__global__ __launch_bounds__(256) void gemm_final(
    const unsigned short* __restrict__ A1, const unsigned short* __restrict__ B1,
    const unsigned short* __restrict__ A2, const unsigned short* __restrict__ B2,
    const float* __restrict__ bias_c, float* __restrict__ C)
{
  __shared__ unsigned short lds[32768];

  const int nwg = 1664;
  const int lin = blockIdx.x;
  const int swz = (lin & 7) * (nwg >> 3) + (lin >> 3);
  const int brow = (swz >> 2) * 64;
  const int bcol = (swz & 3) * 64;

  const int tid  = threadIdx.x;
  const int wid  = tid >> 6, lane = tid & 63;
  const int wr   = wid >> 1, wc = wid & 1;
  const int fr   = lane & 15, fg = lane >> 4;

  auto stage = [&](const unsigned short* A, const unsigned short* Bt) {
    const int r0   = lane >> 3;
    const int slot = lane & 7;
    #pragma unroll
    for (int t = 0; t < 4; ++t) {
      #pragma unroll
      for (int c = 0; c < 2; ++c) {
        const int row = (wid * 2 + c) * 8 + r0;
        const int gsl = slot ^ (row & 7);
        gl_lds16(A  + (size_t)(brow + row) * 256 + t * 64 + (gsl << 3),
                 &lds[t * 4096 + (wid * 2 + c) * 512]);
        gl_lds16(Bt + (size_t)(bcol + row) * 256 + t * 64 + (gsl << 3),
                 &lds[16384 + t * 4096 + (wid * 2 + c) * 512]);
      }
    }
  };

  f32x4 acc[2][2];
  #pragma unroll
  for (int m = 0; m < 2; ++m)
    #pragma unroll
    for (int n = 0; n < 2; ++n)
      acc[m][n] = (f32x4){0.f, 0.f, 0.f, 0.f};

  auto compute = [&]() {
    #pragma unroll
    for (int t = 0; t < 4; ++t) {
      const char* as = (const char*)&lds[t * 4096];
      const char* bs = (const char*)&lds[16384 + t * 4096];
      #pragma unroll
      for (int kk = 0; kk < 2; ++kk) {
        const int kb = kk * 64 + fg * 16;
        bf16x8 af[2], bfv[2];
        #pragma unroll
        for (int m = 0; m < 2; ++m) {
          const int r = wr * 32 + m * 16 + fr;
          af[m] = *(const bf16x8*)(as + r * 128 + (kb ^ ((r & 7) << 4)));
        }
        #pragma unroll
        for (int n = 0; n < 2; ++n) {
          const int r = wc * 32 + n * 16 + fr;
          bfv[n] = *(const bf16x8*)(bs + r * 128 + (kb ^ ((r & 7) << 4)));
        }
        #pragma unroll
        for (int m = 0; m < 2; ++m)
          #pragma unroll
          for (int n = 0; n < 2; ++n)
            acc[m][n] = __builtin_amdgcn_mfma_f32_16x16x32_bf16(af[m], bfv[n], acc[m][n], 0, 0, 0);
      }
    }
  };

  stage(A1, B1);
  __syncthreads();
  compute();
  __syncthreads();          // all LDS reads done before restage
  stage(A2, B2);
  __syncthreads();
  compute();

  // epilogue
  __syncthreads();
  float* csh = (float*)lds;
  const int c0 = bcol + wc * 32 + fr;
  const int c1 = c0 + 16;
  const float bn0 = bias_c[c0];
  const float bn1 = bias_c[c1];
  #pragma unroll
  for (int m = 0; m < 2; ++m)
    #pragma unroll
    for (int j = 0; j < 4; ++j) {
      const int row = wr * 32 + m * 16 + fg * 4 + j;
      csh[row * 64 + wc * 32 + fr]      = acc[m][0][j] + bn0;
      csh[row * 64 + wc * 32 + 16 + fr] = acc[m][1][j] + bn1;
    }
  __syncthreads();
  #pragma unroll
  for (int i = 0; i < 4; ++i) {
    const int rl = i * 16 + (tid >> 4);
    const int gr = brow + rl;
    if (gr >= M_ROWS) continue;
    const int c4 = (tid & 15) * 4;
    *(float4*)&C[(size_t)gr * 256 + bcol + c4] = *(const float4*)&csh[rl * 64 + c4];
  }
}

// ---- deformable sampling: fp8 v, 4 lanes/(q,h), paired x-corners ----
__global__ __launch_bounds__(256) void msda7(
    const unsigned char* __restrict__ v, const unsigned short* __restrict__ oa,
    const float* __restrict__ ref, unsigned short* __restrict__ attout)
{
  constexpr int LW[4] = {100, 50, 25, 13};
  constexpr int LS[4] = {0, 10000, 12500, 13125};

  __shared__ int2   sidx[64][17];
  __shared__ float4 swt [64][17];

  const int bid   = blockIdx.x;
  const int h     = bid & 7;          // head == XCD under %8 round-robin
  const int chunk = bid >> 3;
  const int tid   = threadIdx.x;
  const int q     = tid >> 2;
  const int c     = tid & 3;
  const int bq    = chunk * 64 + q;
  const bool active = bq < M_ROWS;
  const int b     = (bq >= NQ) ? 1 : 0;

  if (active) {
    const int l = c;
    const int W = LW[l];
    const float fD = (float)W;
    const unsigned short* oarow = oa + (size_t)bq * 384;

    uint2 lg = *(const uint2*)(oarow + 256 + h * 16 + l * 4);
    float g0 = bfu_lo(lg.x), g1 = bfu_hi(lg.x), g2 = bfu_lo(lg.y), g3 = bfu_hi(lg.y);
    float mx = fmaxf(fmaxf(g0, g1), fmaxf(g2, g3));
    mx = fmaxf(mx, __shfl_xor(mx, 1));
    mx = fmaxf(mx, __shfl_xor(mx, 2));
    float e0 = __expf(g0-mx), e1 = __expf(g1-mx), e2 = __expf(g2-mx), e3 = __expf(g3-mx);
    float s = e0 + e1 + e2 + e3;
    s += __shfl_xor(s, 1);
    s += __shfl_xor(s, 2);
    const float inv = 1.f / s;
    const float ee[4] = {e0*inv, e1*inv, e2*inv, e3*inv};

    uint4 ov = *(const uint4*)(oarow + h * 32 + l * 8);
    const float oxy[8] = {bfu_lo(ov.x), bfu_hi(ov.x), bfu_lo(ov.y), bfu_hi(ov.y),
                          bfu_lo(ov.z), bfu_hi(ov.z), bfu_lo(ov.w), bfu_hi(ov.w)};
    const float rx = ref[(size_t)bq * 8 + l * 2];
    const float ry = ref[(size_t)bq * 8 + l * 2 + 1];
    const int rowbase = b * NV + LS[l];

    #pragma unroll
    for (int j = 0; j < 4; ++j) {
      const float x = fmaf(rx, fD, oxy[2*j])   - 0.5f;
      const float y = fmaf(ry, fD, oxy[2*j+1]) - 0.5f;
      const float x0f = floorf(x), y0f = floorf(y);
      const float lx = x - x0f, ly = y - y0f;
      const int x0 = (int)x0f, y0 = (int)y0f;
      const int y1 = y0 + 1;
      const int xbase = min(max(x0, 0), W - 2);
      const float wx0 = 1.f - lx, wx1 = lx;
      const float we0 = (x0 == xbase     ? wx0 : 0.f) + (x0 == xbase - 1 ? wx1 : 0.f);
      const float we1 = (x0 == xbase + 1 ? wx0 : 0.f) + (x0 == xbase     ? wx1 : 0.f);
      const int cy0 = min(max(y0, 0), W - 1), cy1 = min(max(y1, 0), W - 1);
      const float wy0 = (y0 >= 0 && y0 < W) ? (1.f - ly) : 0.f;
      const float wy1 = (y1 >= 0 && y1 < W) ? ly : 0.f;
      const float wt = ee[j];
      const int p = l * 4 + j;
      sidx[q][p] = make_int2((rowbase + cy0 * W + xbase) * 32,
                             (rowbase + cy1 * W + xbase) * 32);
      swt[q][p] = make_float4(wt * wy0 * we0, wt * wy0 * we1,
                              wt * wy1 * we0, wt * wy1 * we1);
    }
  }
  __syncthreads();

  if (active) {
    const unsigned char* vb = v + (size_t)h * M_ROWS * 32 + c * 16;
    const int el = c >> 1;
    f32x2 acc2[8];
    #pragma unroll
    for (int k = 0; k < 8; ++k) acc2[k] = (f32x2){0.f, 0.f};
    #pragma unroll
    for (int p = 0; p < 16; ++p) {
      const int2   ix = sidx[q][p];
      const float4 w4 = swt[q][p];
      uint4 r0 = *(const uint4*)(vb + ix.x);
      uint4 r1 = *(const uint4*)(vb + ix.y);
      const float wa = el ? w4.y : w4.x;
      const float wb = el ? w4.w : w4.z;
      const f32x2 wav = (f32x2){wa, wa};
      const f32x2 wbv = (f32x2){wb, wb};
      acc2[0] = wav * __builtin_amdgcn_cvt_pk_f32_fp8(r0.x, 0) + acc2[0];
      acc2[1] = wav * __builtin_amdgcn_cvt_pk_f32_fp8(r0.x, 1) + acc2[1];
      acc2[2] = wav * __builtin_amdgcn_cvt_pk_f32_fp8(r0.y, 0) + acc2[2];
      acc2[3] = wav * __builtin_amdgcn_cvt_pk_f32_fp8(r0.y, 1) + acc2[3];
      acc2[4] = wav * __builtin_amdgcn_cvt_pk_f32_fp8(r0.z, 0) + acc2[4];
      acc2[5] = wav * __builtin_amdgcn_cvt_pk_f32_fp8(r0.z, 1) + acc2[5];
      acc2[6] = wav * __builtin_amdgcn_cvt_pk_f32_fp8(r0.w, 0) + acc2[6];
      acc2[7] = wav * __builtin_amdgcn_cvt_pk_f32_fp8(r0.w, 1) + acc2[7];
      acc2[0] = wbv * __builtin_amdgcn_cvt_pk_f32_fp8(r1.x, 0) + acc2[0];
      acc2[1] = wbv * __builtin_amdgcn_cvt_pk_f32_fp8(r1.x, 1) + acc2[1];
      acc2[2] = wbv * __builtin_amdgcn_cvt_pk_f32_fp8(r1.y, 0) + acc2[2];
      acc2[3] = wbv * __builtin_amdgcn_cvt_pk_f32_fp8(r1.y, 1) + acc2[3];
      acc2[4] = wbv * __builtin_amdgcn_cvt_pk_f32_fp8(r1.z, 0) + acc2[4];
      acc2[5] = wbv * __builtin_amdgcn_cvt_pk_f32_fp8(r1.z, 1) + acc2[5];
      acc2[6] = wbv * __builtin_amdgcn_cvt_pk_f32_fp8(r1.w, 0) + acc2[6];
      acc2[7] = wbv * __builtin_amdgcn_cvt_pk_f32_fp8(r1.w, 1) + acc2[7];
    }
    #pragma unroll
    for (int k = 0; k < 8; ++k) {
      acc2[k][0] += __shfl_xor(acc2[k][0], 2);
      acc2[k][1] += __shfl_xor(acc2[k][1], 2);
    }
    if (c < 2) {
      uint4 pkA, pkB;
      pkA.x = pk2(acc2[0][0], acc2[0][1]);
      pkA.y = pk2(acc2[1][0], acc2[1][1]);
      pkA.z = pk2(acc2[2][0], acc2[2][1]);
      pkA.w = pk2(acc2[3][0], acc2[3][1]);
      pkB.x = pk2(acc2[4][0], acc2[4][1]);
      pkB.y = pk2(acc2[5][0], acc2[5][1]);
      pkB.z = pk2(acc2[6][0], acc2[6][1]);
      pkB.w = pk2(acc2[7][0], acc2[7][1]);
      unsigned short* dst = attout + (size_t)bq * 256 + h * 32 + c * 16;
      *(uint4*)dst = pkA;
      *(uint4*)(dst + 8) = pkB;
    }
  }
}

extern "C" void kernel_launch(void* const* d_in, const int* in_sizes, int n_in,
                              void* d_out, int out_size, void* d_ws, size_t ws_size,
                              hipStream_t stream) {
  const float* query  = (const float*)d_in[0];
  const float* value  = (const float*)d_in[2];
  const float* qpos   = (const float*)d_in[3];
  const float* refpts = (const float*)d_in[4];
  const float* W_value = (const float*)d_in[8];
  const float* b_value = (const float*)d_in[9];
  const float* W_off   = (const float*)d_in[10];
  const float* b_off   = (const float*)d_in[11];
  const float* W_attn  = (const float*)d_in[12];
  const float* b_attn  = (const float*)d_in[13];
  const float* W_out   = (const float*)d_in[14];
  const float* b_out   = (const float*)d_in[15];
  const float* W_ffn   = (const float*)d_in[16];
  const float* b_ffn   = (const float*)d_in[17];
  float* out = (float*)d_out;

  // workspace layout (~69 MB)
  unsigned short* oa    = (unsigned short*)d_ws;                     // (MP,384) bf16
  unsigned char*  vbuf8 = (unsigned char*)(oa + (size_t)MP * 384);   // [8][M][32] fp8
  unsigned short* AB1   = (unsigned short*)(vbuf8 + (size_t)8 * M_ROWS * 32); // val_bf -> attout
  unsigned short* QB    = AB1 + (size_t)MP * 256;                    // query+qpos bf16
  unsigned short* Q2B   = QB + (size_t)MP * 256;                     // query bf16
  unsigned short* wts   = Q2B + (size_t)MP * 256;                    // 294912 shorts
  unsigned short* wv_t  = wts;
  unsigned short* woa_t = wts + 65536;     // [W_off^T ; W_attn^T]
  unsigned short* wf_t  = wts + 163840;    // W_ffn^T
  unsigned short* wu_bf = wts + 229376;    // W_out bf16 [k][j]
  unsigned short* wof_t = wts + 294912;    // (W_out@W_ffn)^T bf16, 65536 shorts
  float*          bias_c = (float*)(wof_t + 65536);  // 256 f32

  const dim3 blk(256);

  // DMA-staged prep: 416 value + 831 query + 64 weights + 1 bias
  prep_dma<<<dim3(1312), blk, 0, stream>>>(value, query, qpos, AB1, QB, Q2B,
      W_value, W_off, W_attn, W_out, W_ffn, wts, bias_c, b_out, b_ffn);

  // merged: v-GEMM (fp8) + oa-GEMM (bf16) + Wof GEMM (16 blocks)
  gemm_voa2<<<dim3(1664 + 2496 + 16), blk, 0, stream>>>(
      AB1, QB, wv_t, woa_t, wf_t, wu_bf, b_value, b_off, b_attn, vbuf8, oa, wof_t);

  // deformable sampling -> attout bf16 (overwrites AB1)
  msda7<<<dim3(8 * 416), blk, 0, stream>>>(vbuf8, oa, refpts, AB1);

  // out = attout@Wof^T + query_bf@Wffn^T + bias_c  (K=512, f32 out)
  gemm_final<<<dim3(1664), blk, 0, stream>>>(AB1, wof_t, Q2B, wf_t, bias_c, out);
}

// Round 22
// 105.876 us; speedup vs baseline: 1.1737x; 1.0158x over previous
//
#include <hip/hip_runtime.h>
#include <hip/hip_bf16.h>
#include <math.h>

#define NQ 13294
#define NV 13294
#define M_ROWS (2*NQ)     // 26588
#define MP 26624          // padded row count (416*64)

typedef __attribute__((ext_vector_type(8))) short bf16x8;
typedef __attribute__((ext_vector_type(4))) float f32x4;
typedef __attribute__((ext_vector_type(2))) float f32x2;

__device__ __forceinline__ float bfu_lo(unsigned int u){ return __uint_as_float(u << 16); }
__device__ __forceinline__ float bfu_hi(unsigned int u){ return __uint_as_float(u & 0xffff0000u); }
__device__ __forceinline__ unsigned short f2bf(float f){
  unsigned int u = __float_as_uint(f);
  u += 0x7fffu + ((u >> 16) & 1u);   // RNE
  return (unsigned short)(u >> 16);
}
__device__ __forceinline__ unsigned int pk2(float a, float b){
  return (unsigned int)f2bf(a) | ((unsigned int)f2bf(b) << 16);
}
__device__ __forceinline__ void gl_lds16(const void* g, void* l) {
  __builtin_amdgcn_global_load_lds(
      (const __attribute__((address_space(1))) unsigned int*)g,
      (__attribute__((address_space(3))) unsigned int*)l, 16, 0, 0);
}

// ---- prep via LDS-DMA staging, 32KB tiles -> 4 blocks/CU so fill(DMA) and
// drain(pack+store) phases of different blocks overlap on each CU.
// [0,831): value -> val_bf            (8192 f32 DMA -> 16KB bf16)
// [831,2493): query,qpos -> q_bf,q2_bf (4096+4096 f32 DMA -> 2x8KB bf16)
// [2493,2557): weight transposes + wu copy
// 2557: bias_c
__global__ __launch_bounds__(256) void prep_dma(
    const float* __restrict__ value, const float* __restrict__ query,
    const float* __restrict__ qpos,
    unsigned short* __restrict__ val_bf, unsigned short* __restrict__ q_bf,
    unsigned short* __restrict__ q2_bf,
    const float* __restrict__ wv, const float* __restrict__ wo,
    const float* __restrict__ wa, const float* __restrict__ wu,
    const float* __restrict__ wf, unsigned short* __restrict__ wt,
    float* __restrict__ bias_c,
    const float* __restrict__ b_out, const float* __restrict__ b_ffn)
{
  __shared__ float lf[8192];   // 32 KB
  const int bx   = blockIdx.x;
  const int tid  = threadIdx.x;
  const int wid  = tid >> 6, lane = tid & 63;
  const size_t TOT = (size_t)M_ROWS * 256;   // 6,806,528 floats per stream

  if (bx < 831) {
    const size_t base = (size_t)bx * 8192;
    #pragma unroll
    for (int i = 0; i < 8; ++i) {
      const int seg = i * 4 + wid;                 // 0..31 (1KB segments)
      size_t src = base + seg * 256 + lane * 4;
      if (src > TOT - 4) src = TOT - 4;
      gl_lds16(value + src, &lf[seg * 256]);
    }
    __syncthreads();
    #pragma unroll
    for (int r = 0; r < 4; ++r) {
      const int off = r * 2048 + tid * 8;
      const size_t g = base + off;
      if (g + 8 <= TOT) {
        float4 a = *(const float4*)&lf[off];
        float4 b = *(const float4*)&lf[off + 4];
        uint4 pk;
        pk.x = pk2(a.x, a.y); pk.y = pk2(a.z, a.w);
        pk.z = pk2(b.x, b.y); pk.w = pk2(b.z, b.w);
        *(uint4*)(val_bf + g) = pk;
      }
    }
  } else if (bx < 2493) {
    const size_t base = (size_t)(bx - 831) * 4096;
    #pragma unroll
    for (int i = 0; i < 4; ++i) {
      const int seg = i * 4 + wid;                 // 0..15
      size_t src = base + seg * 256 + lane * 4;
      if (src > TOT - 4) src = TOT - 4;
      gl_lds16(query + src, &lf[seg * 256]);
      gl_lds16(qpos  + src, &lf[4096 + seg * 256]);
    }
    __syncthreads();
    #pragma unroll
    for (int r = 0; r < 2; ++r) {
      const int off = r * 2048 + tid * 8;
      const size_t g = base + off;
      if (g + 8 <= TOT) {
        float4 q0 = *(const float4*)&lf[off];
        float4 q1 = *(const float4*)&lf[off + 4];
        float4 p0 = *(const float4*)&lf[4096 + off];
        float4 p1 = *(const float4*)&lf[4096 + off + 4];
        uint4 pkq;
        pkq.x = pk2(q0.x, q0.y); pkq.y = pk2(q0.z, q0.w);
        pkq.z = pk2(q1.x, q1.y); pkq.w = pk2(q1.z, q1.w);
        *(uint4*)(q2_bf + g) = pkq;
        uint4 pks;
        pks.x = pk2(q0.x + p0.x, q0.y + p0.y);
        pks.y = pk2(q0.z + p0.z, q0.w + p0.w);
        pks.z = pk2(q1.x + p1.x, q1.y + p1.y);
        pks.w = pk2(q1.z + p1.z, q1.w + p1.w);
        *(uint4*)(q_bf + g) = pks;
      }
    }
  } else if (bx < 2557) {
    for (int t = (bx - 2493) * 256 + tid; t < 294912; t += 64 * 256) {
      if (t < 229376) {
        const float* src; int Nn; int base2;
        if      (t < 65536)  { src = wv; Nn = 256; base2 = 0; }
        else if (t < 131072) { src = wo; Nn = 256; base2 = 65536; }
        else if (t < 163840) { src = wa; Nn = 128; base2 = 131072; }
        else                 { src = wf; Nn = 256; base2 = 163840; }
        const int local = t - base2;
        const int n = local >> 8, k = local & 255;
        wt[t] = f2bf(src[k * Nn + n]);
      } else {
        wt[t] = f2bf(wu[t - 229376]);   // wu straight copy (coalesced)
      }
    }
  } else {
    // bias_c[n] = sum_k b_out[k]*W_ffn[k][n] + b_ffn[n]
    const int n = tid;
    float acc = b_ffn[n];
    #pragma unroll 8
    for (int k = 0; k < 256; ++k)
      acc = fmaf(b_out[k], wf[k * 256 + n], acc);
    bias_c[n] = acc;
  }
}

// ---- merged GEMM dispatch: v (fp8 head-split) | oa (bf16) | Wof (bf16 256x256) ----
__global__ __launch_bounds__(256) void gemm_voa2(
    const unsigned short* __restrict__ val_bf, const unsigned short* __restrict__ q_bf,
    const unsigned short* __restrict__ wv_t, const unsigned short* __restrict__ woa_t,
    const unsigned short* __restrict__ wf_t, const unsigned short* __restrict__ wu_bf,
    const float* __restrict__ b_value, const float* __restrict__ b_off,
    const float* __restrict__ b_attn,
    unsigned char* __restrict__ vbuf8, unsigned short* __restrict__ oa,
    unsigned short* __restrict__ wof_t)
{
  __shared__ unsigned short lds[32768];   // As [0,16384) | Bs [16384,32768)

  const int bx = blockIdx.x;
  const int mode = (bx < 1664) ? 0 : (bx < 4160) ? 1 : 2;
  const int lin  = (mode == 0) ? bx : (mode == 1) ? bx - 1664 : bx - 4160;
  const int nwg  = (mode == 0) ? 1664 : (mode == 1) ? 2496 : 16;
  const int ncol = (mode == 0) ? 4 : (mode == 1) ? 6 : 4;
  const unsigned short* A  = (mode == 0) ? val_bf : (mode == 1) ? q_bf : wf_t;
  const unsigned short* Bt = (mode == 0) ? wv_t : (mode == 1) ? woa_t : wu_bf;

  const int swz  = (lin & 7) * (nwg >> 3) + (lin >> 3);
  const int brow = (swz / ncol) * 64;
  const int bcol = (swz % ncol) * 64;

  const int tid  = threadIdx.x;
  const int wid  = tid >> 6, lane = tid & 63;
  const int wr   = wid >> 1, wc = wid & 1;
  const int fr   = lane & 15, fg = lane >> 4;

  {
    const int r0   = lane >> 3;
    const int slot = lane & 7;
    #pragma unroll
    for (int t = 0; t < 4; ++t) {
      #pragma unroll
      for (int c = 0; c < 2; ++c) {
        const int row = (wid * 2 + c) * 8 + r0;
        const int gsl = slot ^ (row & 7);
        gl_lds16(A  + (size_t)(brow + row) * 256 + t * 64 + (gsl << 3),
                 &lds[t * 4096 + (wid * 2 + c) * 512]);
        gl_lds16(Bt + (size_t)(bcol + row) * 256 + t * 64 + (gsl << 3),
                 &lds[16384 + t * 4096 + (wid * 2 + c) * 512]);
      }
    }
  }
  __syncthreads();

  f32x4 acc[2][2];
  #pragma unroll
  for (int m = 0; m < 2; ++m)
    #pragma unroll
    for (int n = 0; n < 2; ++n)
      acc[m][n] = (f32x4){0.f, 0.f, 0.f, 0.f};

  #pragma unroll
  for (int t = 0; t < 4; ++t) {
    const char* as = (const char*)&lds[t * 4096];
    const char* bs = (const char*)&lds[16384 + t * 4096];
    #pragma unroll
    for (int kk = 0; kk < 2; ++kk) {
      const int kb = kk * 64 + fg * 16;
      bf16x8 af[2], bfv[2];
      #pragma unroll
      for (int m = 0; m < 2; ++m) {
        const int r = wr * 32 + m * 16 + fr;
        af[m] = *(const bf16x8*)(as + r * 128 + (kb ^ ((r & 7) << 4)));
      }
      #pragma unroll
      for (int n = 0; n < 2; ++n) {
        const int r = wc * 32 + n * 16 + fr;
        bfv[n] = *(const bf16x8*)(bs + r * 128 + (kb ^ ((r & 7) << 4)));
      }
      #pragma unroll
      for (int m = 0; m < 2; ++m)
        #pragma unroll
        for (int n = 0; n < 2; ++n)
          acc[m][n] = __builtin_amdgcn_mfma_f32_16x16x32_bf16(af[m], bfv[n], acc[m][n], 0, 0, 0);
    }
  }

  __syncthreads();
  float* csh = (float*)lds;
  const int c0 = bcol + wc * 32 + fr;
  const int c1 = c0 + 16;
  float bn0 = 0.f, bn1 = 0.f;
  if (mode == 0) { bn0 = b_value[c0]; bn1 = b_value[c1]; }
  else if (mode == 1) {
    bn0 = (c0 < 256) ? b_off[c0] : b_attn[c0 - 256];
    bn1 = (c1 < 256) ? b_off[c1] : b_attn[c1 - 256];
  }
  #pragma unroll
  for (int m = 0; m < 2; ++m)
    #pragma unroll
    for (int j = 0; j < 4; ++j) {
      const int row = wr * 32 + m * 16 + fg * 4 + j;
      csh[row * 64 + wc * 32 + fr]      = acc[m][0][j] + bn0;
      csh[row * 64 + wc * 32 + 16 + fr] = acc[m][1][j] + bn1;
    }
  __syncthreads();
  #pragma unroll
  for (int i = 0; i < 4; ++i) {
    const int rl = i * 16 + (tid >> 4);
    const int gr = brow + rl;
    if (gr >= M_ROWS && mode != 2) continue;
    const int c4 = (tid & 15) * 4;
    float4 v = *(const float4*)&csh[rl * 64 + c4];
    if (mode == 0) {
      const int head = (bcol + c4) >> 5;
      const int ch   = c4 & 31;
      int r = 0;
      r = __builtin_amdgcn_cvt_pk_fp8_f32(v.x, v.y, r, 0);
      r = __builtin_amdgcn_cvt_pk_fp8_f32(v.z, v.w, r, 1);
      *(int*)&vbuf8[((size_t)head * M_ROWS + gr) * 32 + ch] = r;
    } else if (mode == 1) {
      ushort4 pk = make_ushort4(f2bf(v.x), f2bf(v.y), f2bf(v.z), f2bf(v.w));
      *(ushort4*)&oa[(size_t)gr * 384 + bcol + c4] = pk;
    } else {
      ushort4 pk = make_ushort4(f2bf(v.x), f2bf(v.y), f2bf(v.z), f2bf(v.w));
      *(ushort4*)&wof_t[(size_t)gr * 256 + bcol + c4] = pk;
    }
  }
}

// ---- final fused GEMM: out = attout@Wof^T + query_bf@Wffn^T + bias_c  (K=512) ----
__global__ __launch_bounds__(256) void gemm_final(
    const unsigned short* __restrict__ A1, const unsigned short* __restrict__ B1,
    const unsigned short* __restrict__ A2, const unsigned short* __restrict__ B2,
    const float* __restrict__ bias_c, float* __restrict__ C)
{
  __shared__ unsigned short lds[32768];

  const int nwg = 1664;
  const int lin = blockIdx.x;
  const int swz = (lin & 7) * (nwg >> 3) + (lin >> 3);
  const int brow = (swz >> 2) * 64;
  const int bcol = (swz & 3) * 64;

  const int tid  = threadIdx.x;
  const int wid  = tid >> 6, lane = tid & 63;
  const int wr   = wid >> 1, wc = wid & 1;
  const int fr   = lane & 15, fg = lane >> 4;

  auto stage = [&](const unsigned short* A, const unsigned short* Bt) {
    const int r0   = lane >> 3;
    const int slot = lane & 7;
    #pragma unroll
    for (int t = 0; t < 4; ++t) {
      #pragma unroll
      for (int c = 0; c < 2; ++c) {
        const int row = (wid * 2 + c) * 8 + r0;
        const int gsl = slot ^ (row & 7);
        gl_lds16(A  + (size_t)(brow + row) * 256 + t * 64 + (gsl << 3),
                 &lds[t * 4096 + (wid * 2 + c) * 512]);
        gl_lds16(Bt + (size_t)(bcol + row) * 256 + t * 64 + (gsl << 3),
                 &lds[16384 + t * 4096 + (wid * 2 + c) * 512]);
      }
    }
  };

  f32x4 acc[2][2];
  #pragma unroll
  for (int m = 0; m < 2; ++m)
    #pragma unroll
    for (int n = 0; n < 2; ++n)
      acc[m][n] = (f32x4){0.f, 0.f, 0.f, 0.f};

  auto compute = [&]() {
    #pragma unroll
    for (int t = 0; t < 4; ++t) {
      const char* as = (const char*)&lds[t * 4096];
      const char* bs = (const char*)&lds[16384 + t * 4096];
      #pragma unroll
      for (int kk = 0; kk < 2; ++kk) {
        const int kb = kk * 64 + fg * 16;
        bf16x8 af[2], bfv[2];
        #pragma unroll
        for (int m = 0; m < 2; ++m) {
          const int r = wr * 32 + m * 16 + fr;
          af[m] = *(const bf16x8*)(as + r * 128 + (kb ^ ((r & 7) << 4)));
        }
        #pragma unroll
        for (int n = 0; n < 2; ++n) {
          const int r = wc * 32 + n * 16 + fr;
          bfv[n] = *(const bf16x8*)(bs + r * 128 + (kb ^ ((r & 7) << 4)));
        }
        #pragma unroll
        for (int m = 0; m < 2; ++m)
          #pragma unroll
          for (int n = 0; n < 2; ++n)
            acc[m][n] = __builtin_amdgcn_mfma_f32_16x16x32_bf16(af[m], bfv[n], acc[m][n], 0, 0, 0);
      }
    }
  };

  stage(A1, B1);
  __syncthreads();
  compute();
  __syncthreads();          // all LDS reads done before restage
  stage(A2, B2);
  __syncthreads();
  compute();

  // epilogue
  __syncthreads();
  float* csh = (float*)lds;
  const int c0 = bcol + wc * 32 + fr;
  const int c1 = c0 + 16;
  const float bn0 = bias_c[c0];
  const float bn1 = bias_c[c1];
  #pragma unroll
  for (int m = 0; m < 2; ++m)
    #pragma unroll
    for (int j = 0; j < 4; ++j) {
      const int row = wr * 32 + m * 16 + fg * 4 + j;
      csh[row * 64 + wc * 32 + fr]      = acc[m][0][j] + bn0;
      csh[row * 64 + wc * 32 + 16 + fr] = acc[m][1][j] + bn1;
    }
  __syncthreads();
  #pragma unroll
  for (int i = 0; i < 4; ++i) {
    const int rl = i * 16 + (tid >> 4);
    const int gr = brow + rl;
    if (gr >= M_ROWS) continue;
    const int c4 = (tid & 15) * 4;
    *(float4*)&C[(size_t)gr * 256 + bcol + c4] = *(const float4*)&csh[rl * 64 + c4];
  }
}

// ---- deformable sampling: fp8 v, 4 lanes/(q,h), paired x-corners ----
__global__ __launch_bounds__(256) void msda7(
    const unsigned char* __restrict__ v, const unsigned short* __restrict__ oa,
    const float* __restrict__ ref, unsigned short* __restrict__ attout)
{
  constexpr int LW[4] = {100, 50, 25, 13};
  constexpr int LS[4] = {0, 10000, 12500, 13125};

  __shared__ int2   sidx[64][17];
  __shared__ float4 swt [64][17];

  const int bid   = blockIdx.x;
  const int h     = bid & 7;          // head == XCD under %8 round-robin
  const int chunk = bid >> 3;
  const int tid   = threadIdx.x;
  const int q     = tid >> 2;
  const int c     = tid & 3;
  const int bq    = chunk * 64 + q;
  const bool active = bq < M_ROWS;
  const int b     = (bq >= NQ) ? 1 : 0;

  if (active) {
    const int l = c;
    const int W = LW[l];
    const float fD = (float)W;
    const unsigned short* oarow = oa + (size_t)bq * 384;

    uint2 lg = *(const uint2*)(oarow + 256 + h * 16 + l * 4);
    float g0 = bfu_lo(lg.x), g1 = bfu_hi(lg.x), g2 = bfu_lo(lg.y), g3 = bfu_hi(lg.y);
    float mx = fmaxf(fmaxf(g0, g1), fmaxf(g2, g3));
    mx = fmaxf(mx, __shfl_xor(mx, 1));
    mx = fmaxf(mx, __shfl_xor(mx, 2));
    float e0 = __expf(g0-mx), e1 = __expf(g1-mx), e2 = __expf(g2-mx), e3 = __expf(g3-mx);
    float s = e0 + e1 + e2 + e3;
    s += __shfl_xor(s, 1);
    s += __shfl_xor(s, 2);
    const float inv = 1.f / s;
    const float ee[4] = {e0*inv, e1*inv, e2*inv, e3*inv};

    uint4 ov = *(const uint4*)(oarow + h * 32 + l * 8);
    const float oxy[8] = {bfu_lo(ov.x), bfu_hi(ov.x), bfu_lo(ov.y), bfu_hi(ov.y),
                          bfu_lo(ov.z), bfu_hi(ov.z), bfu_lo(ov.w), bfu_hi(ov.w)};
    const float rx = ref[(size_t)bq * 8 + l * 2];
    const float ry = ref[(size_t)bq * 8 + l * 2 + 1];
    const int rowbase = b * NV + LS[l];

    #pragma unroll
    for (int j = 0; j < 4; ++j) {
      const float x = fmaf(rx, fD, oxy[2*j])   - 0.5f;
      const float y = fmaf(ry, fD, oxy[2*j+1]) - 0.5f;
      const float x0f = floorf(x), y0f = floorf(y);
      const float lx = x - x0f, ly = y - y0f;
      const int x0 = (int)x0f, y0 = (int)y0f;
      const int y1 = y0 + 1;
      const int xbase = min(max(x0, 0), W - 2);
      const float wx0 = 1.f - lx, wx1 = lx;
      const float we0 = (x0 == xbase     ? wx0 : 0.f) + (x0 == xbase - 1 ? wx1 : 0.f);
      const float we1 = (x0 == xbase + 1 ? wx0 : 0.f) + (x0 == xbase     ? wx1 : 0.f);
      const int cy0 = min(max(y0, 0), W - 1), cy1 = min(max(y1, 0), W - 1);
      const float wy0 = (y0 >= 0 && y0 < W) ? (1.f - ly) : 0.f;
      const float wy1 = (y1 >= 0 && y1 < W) ? ly : 0.f;
      const float wt = ee[j];
      const int p = l * 4 + j;
      sidx[q][p] = make_int2((rowbase + cy0 * W + xbase) * 32,
                             (rowbase + cy1 * W + xbase) * 32);
      swt[q][p] = make_float4(wt * wy0 * we0, wt * wy0 * we1,
                              wt * wy1 * we0, wt * wy1 * we1);
    }
  }
  __syncthreads();

  if (active) {
    const unsigned char* vb = v + (size_t)h * M_ROWS * 32 + c * 16;
    const int el = c >> 1;
    f32x2 acc2[8];
    #pragma unroll
    for (int k = 0; k < 8; ++k) acc2[k] = (f32x2){0.f, 0.f};
    #pragma unroll
    for (int p = 0; p < 16; ++p) {
      const int2   ix = sidx[q][p];
      const float4 w4 = swt[q][p];
      uint4 r0 = *(const uint4*)(vb + ix.x);
      uint4 r1 = *(const uint4*)(vb + ix.y);
      const float wa = el ? w4.y : w4.x;
      const float wb = el ? w4.w : w4.z;
      const f32x2 wav = (f32x2){wa, wa};
      const f32x2 wbv = (f32x2){wb, wb};
      acc2[0] = wav * __builtin_amdgcn_cvt_pk_f32_fp8(r0.x, 0) + acc2[0];
      acc2[1] = wav * __builtin_amdgcn_cvt_pk_f32_fp8(r0.x, 1) + acc2[1];
      acc2[2] = wav * __builtin_amdgcn_cvt_pk_f32_fp8(r0.y, 0) + acc2[2];
      acc2[3] = wav * __builtin_amdgcn_cvt_pk_f32_fp8(r0.y, 1) + acc2[3];
      acc2[4] = wav * __builtin_amdgcn_cvt_pk_f32_fp8(r0.z, 0) + acc2[4];
      acc2[5] = wav * __builtin_amdgcn_cvt_pk_f32_fp8(r0.z, 1) + acc2[5];
      acc2[6] = wav * __builtin_amdgcn_cvt_pk_f32_fp8(r0.w, 0) + acc2[6];
      acc2[7] = wav * __builtin_amdgcn_cvt_pk_f32_fp8(r0.w, 1) + acc2[7];
      acc2[0] = wbv * __builtin_amdgcn_cvt_pk_f32_fp8(r1.x, 0) + acc2[0];
      acc2[1] = wbv * __builtin_amdgcn_cvt_pk_f32_fp8(r1.x, 1) + acc2[1];
      acc2[2] = wbv * __builtin_amdgcn_cvt_pk_f32_fp8(r1.y, 0) + acc2[2];
      acc2[3] = wbv * __builtin_amdgcn_cvt_pk_f32_fp8(r1.y, 1) + acc2[3];
      acc2[4] = wbv * __builtin_amdgcn_cvt_pk_f32_fp8(r1.z, 0) + acc2[4];
      acc2[5] = wbv * __builtin_amdgcn_cvt_pk_f32_fp8(r1.z, 1) + acc2[5];
      acc2[6] = wbv * __builtin_amdgcn_cvt_pk_f32_fp8(r1.w, 0) + acc2[6];
      acc2[7] = wbv * __builtin_amdgcn_cvt_pk_f32_fp8(r1.w, 1) + acc2[7];
    }
    #pragma unroll
    for (int k = 0; k < 8; ++k) {
      acc2[k][0] += __shfl_xor(acc2[k][0], 2);
      acc2[k][1] += __shfl_xor(acc2[k][1], 2);
    }
    if (c < 2) {
      uint4 pkA, pkB;
      pkA.x = pk2(acc2[0][0], acc2[0][1]);
      pkA.y = pk2(acc2[1][0], acc2[1][1]);
      pkA.z = pk2(acc2[2][0], acc2[2][1]);
      pkA.w = pk2(acc2[3][0], acc2[3][1]);
      pkB.x = pk2(acc2[4][0], acc2[4][1]);
      pkB.y = pk2(acc2[5][0], acc2[5][1]);
      pkB.z = pk2(acc2[6][0], acc2[6][1]);
      pkB.w = pk2(acc2[7][0], acc2[7][1]);
      unsigned short* dst = attout + (size_t)bq * 256 + h * 32 + c * 16;
      *(uint4*)dst = pkA;
      *(uint4*)(dst + 8) = pkB;
    }
  }
}

extern "C" void kernel_launch(void* const* d_in, const int* in_sizes, int n_in,
                              void* d_out, int out_size, void* d_ws, size_t ws_size,
                              hipStream_t stream) {
  const float* query  = (const float*)d_in[0];
  const float* value  = (const float*)d_in[2];
  const float* qpos   = (const float*)d_in[3];
  const float* refpts = (const float*)d_in[4];
  const float* W_value = (const float*)d_in[8];
  const float* b_value = (const float*)d_in[9];
  const float* W_off   = (const float*)d_in[10];
  const float* b_off   = (const float*)d_in[11];
  const float* W_attn  = (const float*)d_in[12];
  const float* b_attn  = (const float*)d_in[13];
  const float* W_out   = (const float*)d_in[14];
  const float* b_out   = (const float*)d_in[15];
  const float* W_ffn   = (const float*)d_in[16];
  const float* b_ffn   = (const float*)d_in[17];
  float* out = (float*)d_out;

  // workspace layout (~69 MB)
  unsigned short* oa    = (unsigned short*)d_ws;                     // (MP,384) bf16
  unsigned char*  vbuf8 = (unsigned char*)(oa + (size_t)MP * 384);   // [8][M][32] fp8
  unsigned short* AB1   = (unsigned short*)(vbuf8 + (size_t)8 * M_ROWS * 32); // val_bf -> attout
  unsigned short* QB    = AB1 + (size_t)MP * 256;                    // query+qpos bf16
  unsigned short* Q2B   = QB + (size_t)MP * 256;                     // query bf16
  unsigned short* wts   = Q2B + (size_t)MP * 256;                    // 294912 shorts
  unsigned short* wv_t  = wts;
  unsigned short* woa_t = wts + 65536;     // [W_off^T ; W_attn^T]
  unsigned short* wf_t  = wts + 163840;    // W_ffn^T
  unsigned short* wu_bf = wts + 229376;    // W_out bf16 [k][j]
  unsigned short* wof_t = wts + 294912;    // (W_out@W_ffn)^T bf16, 65536 shorts
  float*          bias_c = (float*)(wof_t + 65536);  // 256 f32

  const dim3 blk(256);

  // DMA-staged prep, 32KB tiles (4 blocks/CU): 831 value + 1662 query + 64 w + 1 bias
  prep_dma<<<dim3(2558), blk, 0, stream>>>(value, query, qpos, AB1, QB, Q2B,
      W_value, W_off, W_attn, W_out, W_ffn, wts, bias_c, b_out, b_ffn);

  // merged: v-GEMM (fp8) + oa-GEMM (bf16) + Wof GEMM (16 blocks)
  gemm_voa2<<<dim3(1664 + 2496 + 16), blk, 0, stream>>>(
      AB1, QB, wv_t, woa_t, wf_t, wu_bf, b_value, b_off, b_attn, vbuf8, oa, wof_t);

  // deformable sampling -> attout bf16 (overwrites AB1)
  msda7<<<dim3(8 * 416), blk, 0, stream>>>(vbuf8, oa, refpts, AB1);

  // out = attout@Wof^T + query_bf@Wffn^T + bias_c  (K=512, f32 out)
  gemm_final<<<dim3(1664), blk, 0, stream>>>(AB1, wof_t, Q2B, wf_t, bias_c, out);
}